// Round 2
// baseline (183.127 us; speedup 1.0000x reference)
//
#include <hip/hip_runtime.h>
#include <hip/hip_bf16.h>

#define LSEQ   1024
#define NHEAD  8
#define DH     64
#define DIM    512
#define CHUNK  64
#define NCHUNK 16   // LSEQ / CHUNK
#define NHTOT  16   // N * NHEAD
#define PAD    68   // LDS row pad (floats): float4-aligned, breaks pow2 strides

__device__ __forceinline__ float softplusf_(float x) {
    if (x > 20.f) return x;
    return log1pf(expf(x));
}

// ---------------------------------------------------------------------------
// Kernel A: q = softplus(query @ Wq^T), k = softplus(key @ Wk^T), v = key @ Wv^T
// out layout [n*H + h][l][d] f32.  64x64 output tile / block, 4x4 per thread.
// LDS tiles stored K-major (transposed) so the inner loop is 2x ds_read_b128.
// ---------------------------------------------------------------------------
__global__ __launch_bounds__(256) void proj_kernel(
    const float* __restrict__ query,
    const float* __restrict__ key,
    const float* __restrict__ Wq,
    const float* __restrict__ Wk,
    const float* __restrict__ Wv,
    float* __restrict__ qbuf,
    float* __restrict__ kbuf,
    float* __restrict__ vbuf)
{
    const int mt  = blockIdx.x;   // 32 tiles over M = N*L = 2048
    const int ot  = blockIdx.y;   // 8 tiles over O = 512
    const int sel = blockIdx.z;   // 0:q 1:k 2:v
    const int t   = threadIdx.x;

    const float* __restrict__ X = (sel == 0) ? query : key;
    const float* __restrict__ W = (sel == 0) ? Wq : (sel == 1) ? Wk : Wv;
    float* __restrict__ obuf = (sel == 0) ? qbuf : (sel == 1) ? kbuf : vbuf;

    __shared__ float Xs[64][PAD];  // [kk][r]
    __shared__ float Ws[64][PAD];  // [kk][c]

    const int m0 = mt * 64, o0 = ot * 64;
    const int r0 = (t >> 4) * 4;        // 4 output rows per thread
    const int c0 = (t & 15) * 4;        // 4 output cols per thread
    const int kk_ld = t & 63;
    const int rg = (t >> 6) * 16;

    float acc[4][4] = {};

    for (int kt = 0; kt < DIM; kt += 64) {
        #pragma unroll
        for (int j = 0; j < 16; ++j) {
            const int r = rg + j;
            Xs[kk_ld][r] = X[(size_t)(m0 + r) * DIM + kt + kk_ld];
            Ws[kk_ld][r] = W[(size_t)(o0 + r) * DIM + kt + kk_ld];
        }
        __syncthreads();
        #pragma unroll 4
        for (int kk = 0; kk < 64; ++kk) {
            const float4 xv = *(const float4*)&Xs[kk][r0];
            const float4 wv = *(const float4*)&Ws[kk][c0];
            acc[0][0] += xv.x * wv.x; acc[0][1] += xv.x * wv.y;
            acc[0][2] += xv.x * wv.z; acc[0][3] += xv.x * wv.w;
            acc[1][0] += xv.y * wv.x; acc[1][1] += xv.y * wv.y;
            acc[1][2] += xv.y * wv.z; acc[1][3] += xv.y * wv.w;
            acc[2][0] += xv.z * wv.x; acc[2][1] += xv.z * wv.y;
            acc[2][2] += xv.z * wv.z; acc[2][3] += xv.z * wv.w;
            acc[3][0] += xv.w * wv.x; acc[3][1] += xv.w * wv.y;
            acc[3][2] += xv.w * wv.z; acc[3][3] += xv.w * wv.w;
        }
        __syncthreads();
    }

    const int o = o0 + c0;
    const int h = o >> 6;          // constant across the 4 cols (c0 % 4 == 0)
    const int d = o & (DH - 1);
    #pragma unroll
    for (int i = 0; i < 4; ++i) {
        const int m = m0 + r0 + i;
        const int n = m >> 10, l = m & (LSEQ - 1);
        float4 vv;
        vv.x = acc[i][0]; vv.y = acc[i][1]; vv.z = acc[i][2]; vv.w = acc[i][3];
        if (sel < 2) {
            vv.x = softplusf_(vv.x); vv.y = softplusf_(vv.y);
            vv.z = softplusf_(vv.z); vv.w = softplusf_(vv.w);
        }
        *(float4*)&obuf[(((size_t)(n * NHEAD + h)) * LSEQ + l) * DH + d] = vv;
    }
}

// ---------------------------------------------------------------------------
// Kernel B: per-(n,h,chunk) sums for the 3 branches:
//   Ssum[br][nh][c][d][e] = sum_{k in chunk} kf_br[k][d] * v[k][e]
//   zsum[br][nh][c][d]    = sum_{k in chunk} kf_br[k][d]
// kf_br = k_plain * {1, cos(pos*w), sin(pos*w)}
// ---------------------------------------------------------------------------
__global__ __launch_bounds__(256) void chunksum_kernel(
    const float* __restrict__ kbuf,
    const float* __restrict__ vbuf,
    const float* __restrict__ pw,
    float* __restrict__ Ssum,
    float* __restrict__ zsum)
{
    const int c  = blockIdx.x;
    const int nh = blockIdx.y;
    const int h  = nh & (NHEAD - 1);
    const int t  = threadIdx.x;

    __shared__ float kf[CHUNK][PAD];   // [k][d] for current branch
    __shared__ float vt[CHUNK][PAD];   // [k][e]

    const size_t base = ((size_t)nh * LSEQ + (size_t)c * CHUNK) * DH;
    const int dcol = t & 63;
    const int rg = (t >> 6) * 16;

    const float w = pw[h * DH + dcol];

    float kpl[16];
    #pragma unroll
    for (int j = 0; j < 16; ++j) {
        const int k = rg + j;
        kpl[j] = kbuf[base + (size_t)k * DH + dcol];
        vt[k][dcol] = vbuf[base + (size_t)k * DH + dcol];
    }

    const int d0 = (t >> 4) * 4;
    const int e0 = (t & 15) * 4;

    for (int br = 0; br < 3; ++br) {
        __syncthreads();   // previous branch's readers done before kf overwrite
        #pragma unroll
        for (int j = 0; j < 16; ++j) {
            const int k = rg + j;
            float f = 1.f;
            const float pos = (float)(c * CHUNK + k);
            if (br == 1) f = cosf(pos * w);
            else if (br == 2) f = sinf(pos * w);
            kf[k][dcol] = kpl[j] * f;
        }
        __syncthreads();

        float S[4][4] = {};
        float zr[4] = {};
        #pragma unroll 4
        for (int k = 0; k < CHUNK; ++k) {
            const float4 kv = *(const float4*)&kf[k][d0];
            const float4 ve = *(const float4*)&vt[k][e0];
            S[0][0] += kv.x * ve.x; S[0][1] += kv.x * ve.y;
            S[0][2] += kv.x * ve.z; S[0][3] += kv.x * ve.w;
            S[1][0] += kv.y * ve.x; S[1][1] += kv.y * ve.y;
            S[1][2] += kv.y * ve.z; S[1][3] += kv.y * ve.w;
            S[2][0] += kv.z * ve.x; S[2][1] += kv.z * ve.y;
            S[2][2] += kv.z * ve.z; S[2][3] += kv.z * ve.w;
            S[3][0] += kv.w * ve.x; S[3][1] += kv.w * ve.y;
            S[3][2] += kv.w * ve.z; S[3][3] += kv.w * ve.w;
            zr[0] += kv.x; zr[1] += kv.y; zr[2] += kv.z; zr[3] += kv.w;
        }

        float* Sg = Ssum + ((size_t)(br * NHTOT + nh) * NCHUNK + c) * (DH * DH);
        #pragma unroll
        for (int i = 0; i < 4; ++i) {
            float4 o;
            o.x = S[i][0]; o.y = S[i][1]; o.z = S[i][2]; o.w = S[i][3];
            *(float4*)&Sg[(d0 + i) * DH + e0] = o;
        }
        if ((t & 15) == 0) {
            float* zg = zsum + ((size_t)(br * NHTOT + nh) * NCHUNK + c) * DH;
            #pragma unroll
            for (int i = 0; i < 4; ++i) zg[d0 + i] = zr[i];
        }
    }
}

// ---------------------------------------------------------------------------
// Kernel C: per-(n,h,chunk) output.
//   num[l][e] = sum_br qf_br[l]·S_prefix_br[:,e]  +  sum_{k<=l in chunk} A[l][k] v[k][e]
//   den[l]    = sum_br qf_br[l]·z_prefix_br       +  sum_{k<=l in chunk} A[l][k]
//   A[l][k]   = sum_br qf_br[l]·kf_br[k]   (= q·k·(1+cos(pq-pk)) >= 0, q,k>0)
// ---------------------------------------------------------------------------
__global__ __launch_bounds__(256) void attn_kernel(
    const float* __restrict__ qbuf,
    const float* __restrict__ kbuf,
    const float* __restrict__ vbuf,
    const float* __restrict__ Ssum,
    const float* __restrict__ zsum,
    const float* __restrict__ pw,
    const float* __restrict__ pb,
    float* __restrict__ outp)
{
    const int c  = blockIdx.x;
    const int nh = blockIdx.y;
    const int n  = nh >> 3;
    const int h  = nh & (NHEAD - 1);
    const int t  = threadIdx.x;

    __shared__ float Sb[DH][PAD];     // S_prefix [d][e]
    __shared__ float qT[DH][PAD];     // qf transposed [d][l]
    __shared__ float kT[DH][PAD];     // kf transposed [d][k]
    __shared__ float vt[CHUNK][PAD];  // [k][e]
    __shared__ float At[CHUNK][PAD];  // masked scores, transposed [k][l]
    __shared__ float zl[DH];
    __shared__ float dl[CHUNK];

    const int l0 = (t >> 4) * 4;
    const int e0 = (t & 15) * 4;      // doubles as k0 for the A block

    const size_t base = ((size_t)nh * LSEQ + (size_t)c * CHUNK) * DH;
    const int dcol = t & 63;
    const int rg = (t >> 6) * 16;

    #pragma unroll
    for (int j = 0; j < 16; ++j) {
        const int k = rg + j;
        vt[k][dcol] = vbuf[base + (size_t)k * DH + dcol];
    }

    const float w = pw[h * DH + dcol];
    const float bias = 3.14159265358979323846f / (1.f + expf(-pb[h * DH + dcol]));

    float qpl[16], kpl[16];
    #pragma unroll
    for (int j = 0; j < 16; ++j) {
        const int l = rg + j;
        qpl[j] = qbuf[base + (size_t)l * DH + dcol];
        kpl[j] = kbuf[base + (size_t)l * DH + dcol];
    }

    float num[4][4] = {};
    float Ar[4][4] = {};
    float den[4] = {};

    for (int br = 0; br < 3; ++br) {
        // accumulate chunk-prefix state from global (registers, no LDS yet)
        float sacc[16];
        #pragma unroll
        for (int j = 0; j < 16; ++j) sacc[j] = 0.f;
        float zacc = 0.f;
        const float* Sg = Ssum + (size_t)(br * NHTOT + nh) * NCHUNK * (DH * DH);
        const float* zg = zsum + (size_t)(br * NHTOT + nh) * NCHUNK * DH;
        for (int cp = 0; cp < c; ++cp) {
            const float* Sgc = Sg + (size_t)cp * (DH * DH);
            #pragma unroll
            for (int j = 0; j < 16; ++j) sacc[j] += Sgc[j * 256 + t];
            if (t < 64) zacc += zg[cp * DH + t];
        }
        __syncthreads();   // previous branch's readers done before overwrite
        #pragma unroll
        for (int j = 0; j < 16; ++j) {
            const int f = j * 256 + t;
            Sb[f >> 6][f & 63] = sacc[j];
        }
        if (t < 64) zl[t] = zacc;

        // build feature-mapped q/k tiles (transposed) for this branch
        #pragma unroll
        for (int j = 0; j < 16; ++j) {
            const int l = rg + j;
            const float pos = (float)(c * CHUNK + l);
            float tq = 1.f, tk = 1.f;
            if (br == 1) { tq = cosf(pos * w + bias); tk = cosf(pos * w); }
            else if (br == 2) { tq = sinf(pos * w + bias); tk = sinf(pos * w); }
            qT[dcol][l] = qpl[j] * tq;
            kT[dcol][l] = kpl[j] * tk;
        }
        __syncthreads();

        #pragma unroll 2
        for (int d = 0; d < DH; ++d) {
            const float4 qv = *(const float4*)&qT[d][l0];
            const float4 Sv = *(const float4*)&Sb[d][e0];
            const float4 kv = *(const float4*)&kT[d][e0];
            const float z = zl[d];
            num[0][0] += qv.x * Sv.x; num[0][1] += qv.x * Sv.y;
            num[0][2] += qv.x * Sv.z; num[0][3] += qv.x * Sv.w;
            num[1][0] += qv.y * Sv.x; num[1][1] += qv.y * Sv.y;
            num[1][2] += qv.y * Sv.z; num[1][3] += qv.y * Sv.w;
            num[2][0] += qv.z * Sv.x; num[2][1] += qv.z * Sv.y;
            num[2][2] += qv.z * Sv.z; num[2][3] += qv.z * Sv.w;
            num[3][0] += qv.w * Sv.x; num[3][1] += qv.w * Sv.y;
            num[3][2] += qv.w * Sv.z; num[3][3] += qv.w * Sv.w;
            Ar[0][0] += qv.x * kv.x; Ar[0][1] += qv.x * kv.y;
            Ar[0][2] += qv.x * kv.z; Ar[0][3] += qv.x * kv.w;
            Ar[1][0] += qv.y * kv.x; Ar[1][1] += qv.y * kv.y;
            Ar[1][2] += qv.y * kv.z; Ar[1][3] += qv.y * kv.w;
            Ar[2][0] += qv.z * kv.x; Ar[2][1] += qv.z * kv.y;
            Ar[2][2] += qv.z * kv.z; Ar[2][3] += qv.z * kv.w;
            Ar[3][0] += qv.w * kv.x; Ar[3][1] += qv.w * kv.y;
            Ar[3][2] += qv.w * kv.z; Ar[3][3] += qv.w * kv.w;
            den[0] += qv.x * z; den[1] += qv.y * z;
            den[2] += qv.z * z; den[3] += qv.w * z;
        }
    }

    // write causal-masked scores (transposed) + prefix part of den
    #pragma unroll
    for (int i = 0; i < 4; ++i)
        #pragma unroll
        for (int j = 0; j < 4; ++j) {
            const int l = l0 + i, k = e0 + j;
            At[k][l] = (k <= l) ? Ar[i][j] : 0.f;
        }
    if ((t & 15) == 0) {
        #pragma unroll
        for (int i = 0; i < 4; ++i) dl[l0 + i] = den[i];
    }
    __syncthreads();

    if (t < 64) {   // den intra-chunk: column sums of masked At
        float s = 0.f;
        for (int k = 0; k <= t; ++k) s += At[k][t];
        dl[t] += s;
    }
    __syncthreads();

    // intra-chunk numerator
    #pragma unroll 2
    for (int k = 0; k < CHUNK; ++k) {
        const float4 av = *(const float4*)&At[k][l0];
        const float4 vv = *(const float4*)&vt[k][e0];
        num[0][0] += av.x * vv.x; num[0][1] += av.x * vv.y;
        num[0][2] += av.x * vv.z; num[0][3] += av.x * vv.w;
        num[1][0] += av.y * vv.x; num[1][1] += av.y * vv.y;
        num[1][2] += av.y * vv.z; num[1][3] += av.y * vv.w;
        num[2][0] += av.z * vv.x; num[2][1] += av.z * vv.y;
        num[2][2] += av.z * vv.z; num[2][3] += av.z * vv.w;
        num[3][0] += av.w * vv.x; num[3][1] += av.w * vv.y;
        num[3][2] += av.w * vv.z; num[3][3] += av.w * vv.w;
    }

    #pragma unroll
    for (int i = 0; i < 4; ++i) {
        const int l = c * CHUNK + l0 + i;
        const float inv = 1.f / dl[l0 + i];
        const size_t off = ((size_t)n * LSEQ + l) * DIM + h * DH + e0;
        float4 o;
        o.x = num[i][0] * inv; o.y = num[i][1] * inv;
        o.z = num[i][2] * inv; o.w = num[i][3] * inv;
        *(float4*)&outp[off] = o;
    }
}

extern "C" void kernel_launch(void* const* d_in, const int* in_sizes, int n_in,
                              void* d_out, int out_size, void* d_ws, size_t ws_size,
                              hipStream_t stream) {
    const float* query = (const float*)d_in[0];
    const float* key   = (const float*)d_in[1];
    const float* Wq    = (const float*)d_in[2];
    const float* Wk    = (const float*)d_in[3];
    const float* Wv    = (const float*)d_in[4];
    const float* pw    = (const float*)d_in[5];
    const float* pb    = (const float*)d_in[6];

    float* ws = (float*)d_ws;
    // f32 workspace layout (floats): qbuf/kbuf/vbuf 1M each, Ssum 3M, zsum 48K
    float* qbuf = ws;
    float* kbuf = ws + 1048576;
    float* vbuf = ws + 2097152;
    float* Ssum = ws + 3145728;
    float* zsum = ws + 6291456;   // total 6,340,608 floats = 25.4 MB

    proj_kernel<<<dim3(32, 8, 3), 256, 0, stream>>>(
        query, key, Wq, Wk, Wv, qbuf, kbuf, vbuf);
    chunksum_kernel<<<dim3(NCHUNK, NHTOT), 256, 0, stream>>>(
        kbuf, vbuf, pw, Ssum, zsum);
    attn_kernel<<<dim3(NCHUNK, NHTOT), 256, 0, stream>>>(
        qbuf, kbuf, vbuf, Ssum, zsum, pw, pb, (float*)d_out);
}

// Round 3
// 175.872 us; speedup vs baseline: 1.0413x; 1.0413x over previous
//
#include <hip/hip_runtime.h>
#include <hip/hip_bf16.h>

#define LSEQ   1024
#define NHEAD  8
#define DH     64
#define DIM    512
#define CHUNK  64
#define NCHUNK 16   // LSEQ / CHUNK
#define NHTOT  16   // N * NHEAD
#define PAD    68   // LDS row pad (floats)

typedef __attribute__((ext_vector_type(8))) short short8;
typedef __attribute__((ext_vector_type(4))) float floatx4;

__device__ __forceinline__ float softplusf_(float x) {
    if (x > 20.f) return x;
    return log1pf(expf(x));
}

__device__ __forceinline__ unsigned short bf16_rne(float x) {
    unsigned int u = __float_as_uint(x);
    u += 0x7FFFu + ((u >> 16) & 1u);
    return (unsigned short)(u >> 16);
}

// ---------------------------------------------------------------------------
// Kernel A (MFMA): C = X @ W^T with f32 accuracy via hi/lo bf16 split:
//   x = hi + lo (each bf16);  C ~= Xh@Wh + Xh@Wl + Xl@Wh  (lo*lo ~ 2^-18, dropped)
// 128x128 tile / block, 4 waves of 64x64, 16x16x32 bf16 MFMA, BK=32.
// Epilogue: softplus for q/k, store f32 [n*H+h][l][d].
// ---------------------------------------------------------------------------
#define BK   32
#define LDK  40   // padded row stride in bf16 elems (80 B = 20 banks, 16B-aligned)

__global__ __launch_bounds__(256) void proj_kernel(
    const float* __restrict__ query,
    const float* __restrict__ key,
    const float* __restrict__ Wq,
    const float* __restrict__ Wk,
    const float* __restrict__ Wv,
    float* __restrict__ qbuf,
    float* __restrict__ kbuf,
    float* __restrict__ vbuf)
{
    const int mt  = blockIdx.x;   // 16 tiles over M = 2048
    const int ot  = blockIdx.y;   // 4 tiles over O = 512
    const int sel = blockIdx.z;   // 0:q 1:k 2:v
    const int t   = threadIdx.x;

    const float* __restrict__ X = (sel == 0) ? query : key;
    const float* __restrict__ W = (sel == 0) ? Wq : (sel == 1) ? Wk : Wv;
    float* __restrict__ obuf = (sel == 0) ? qbuf : (sel == 1) ? kbuf : vbuf;

    __shared__ unsigned short Ahi[128 * LDK];
    __shared__ unsigned short Alo[128 * LDK];
    __shared__ unsigned short Bhi[128 * LDK];
    __shared__ unsigned short Blo[128 * LDK];

    const int m0 = mt * 128, o0 = ot * 128;
    const int lane = t & 63, wave = t >> 6;
    const int quad = lane >> 4, l16 = lane & 15;
    const int wm = wave >> 1, wn = wave & 1;   // 2x2 waves of 64x64

    // staging coords: 4 float4 per thread per tile (128 rows x 8 float4/row)
    int srow[4], skq[4];
    #pragma unroll
    for (int i = 0; i < 4; ++i) {
        const int flat = i * 256 + t;
        srow[i] = flat >> 3;
        skq[i]  = (flat & 7) * 4;
    }

    floatx4 acc[4][4];
    #pragma unroll
    for (int i = 0; i < 4; ++i)
        #pragma unroll
        for (int j = 0; j < 4; ++j)
            acc[i][j] = (floatx4){0.f, 0.f, 0.f, 0.f};

    float4 ax[4], bx[4];
    #pragma unroll
    for (int i = 0; i < 4; ++i) {
        ax[i] = *(const float4*)&X[(size_t)(m0 + srow[i]) * DIM + skq[i]];
        bx[i] = *(const float4*)&W[(size_t)(o0 + srow[i]) * DIM + skq[i]];
    }

    for (int kt = 0; kt < DIM; kt += BK) {
        __syncthreads();   // previous step's frag reads done
        #pragma unroll
        for (int i = 0; i < 4; ++i) {
            const float v0[4] = {ax[i].x, ax[i].y, ax[i].z, ax[i].w};
            const float v1[4] = {bx[i].x, bx[i].y, bx[i].z, bx[i].w};
            ushort4 h0, l0, h1, l1;
            unsigned short* ph0 = (unsigned short*)&h0;
            unsigned short* pl0 = (unsigned short*)&l0;
            unsigned short* ph1 = (unsigned short*)&h1;
            unsigned short* pl1 = (unsigned short*)&l1;
            #pragma unroll
            for (int c2 = 0; c2 < 4; ++c2) {
                unsigned short h = bf16_rne(v0[c2]);
                ph0[c2] = h;
                pl0[c2] = bf16_rne(v0[c2] - __uint_as_float(((unsigned int)h) << 16));
                h = bf16_rne(v1[c2]);
                ph1[c2] = h;
                pl1[c2] = bf16_rne(v1[c2] - __uint_as_float(((unsigned int)h) << 16));
            }
            *(ushort4*)&Ahi[srow[i] * LDK + skq[i]] = h0;
            *(ushort4*)&Alo[srow[i] * LDK + skq[i]] = l0;
            *(ushort4*)&Bhi[srow[i] * LDK + skq[i]] = h1;
            *(ushort4*)&Blo[srow[i] * LDK + skq[i]] = l1;
        }
        __syncthreads();

        if (kt + BK < DIM) {   // prefetch next stage, overlaps MFMAs below
            #pragma unroll
            for (int i = 0; i < 4; ++i) {
                ax[i] = *(const float4*)&X[(size_t)(m0 + srow[i]) * DIM + kt + BK + skq[i]];
                bx[i] = *(const float4*)&W[(size_t)(o0 + srow[i]) * DIM + kt + BK + skq[i]];
            }
        }

        short8 ah[4], al[4];
        #pragma unroll
        for (int mi = 0; mi < 4; ++mi) {
            const int r = wm * 64 + mi * 16 + l16;
            ah[mi] = *(const short8*)&Ahi[r * LDK + quad * 8];
            al[mi] = *(const short8*)&Alo[r * LDK + quad * 8];
        }
        #pragma unroll
        for (int ni = 0; ni < 4; ++ni) {
            const int c = wn * 64 + ni * 16 + l16;
            const short8 bh = *(const short8*)&Bhi[c * LDK + quad * 8];
            const short8 bl = *(const short8*)&Blo[c * LDK + quad * 8];
            #pragma unroll
            for (int mi = 0; mi < 4; ++mi) {
                acc[mi][ni] = __builtin_amdgcn_mfma_f32_16x16x32_bf16(ah[mi], bh, acc[mi][ni], 0, 0, 0);
                acc[mi][ni] = __builtin_amdgcn_mfma_f32_16x16x32_bf16(ah[mi], bl, acc[mi][ni], 0, 0, 0);
                acc[mi][ni] = __builtin_amdgcn_mfma_f32_16x16x32_bf16(al[mi], bh, acc[mi][ni], 0, 0, 0);
            }
        }
    }

    // epilogue: C/D layout col = lane&15, row = quad*4 + reg
    #pragma unroll
    for (int mi = 0; mi < 4; ++mi)
        #pragma unroll
        for (int ni = 0; ni < 4; ++ni) {
            const int o = o0 + wn * 64 + ni * 16 + l16;
            const int h = o >> 6, d = o & (DH - 1);
            #pragma unroll
            for (int r = 0; r < 4; ++r) {
                const int m = m0 + wm * 64 + mi * 16 + quad * 4 + r;
                const int n = m >> 10, l = m & (LSEQ - 1);
                float val = acc[mi][ni][r];
                if (sel < 2) val = softplusf_(val);
                obuf[(((size_t)(n * NHEAD + h)) * LSEQ + l) * DH + d] = val;
            }
        }
}

// ---------------------------------------------------------------------------
// Kernel B: per-(n,h,chunk) sums for the 3 branches.
// ---------------------------------------------------------------------------
__global__ __launch_bounds__(256) void chunksum_kernel(
    const float* __restrict__ kbuf,
    const float* __restrict__ vbuf,
    const float* __restrict__ pw,
    float* __restrict__ Ssum,
    float* __restrict__ zsum)
{
    const int c  = blockIdx.x;
    const int nh = blockIdx.y;
    const int h  = nh & (NHEAD - 1);
    const int t  = threadIdx.x;

    __shared__ float kf[CHUNK][PAD];
    __shared__ float vt[CHUNK][PAD];

    const size_t base = ((size_t)nh * LSEQ + (size_t)c * CHUNK) * DH;
    const int dcol = t & 63;
    const int rg = (t >> 6) * 16;

    const float w = pw[h * DH + dcol];

    float kpl[16];
    #pragma unroll
    for (int j = 0; j < 16; ++j) {
        const int k = rg + j;
        kpl[j] = kbuf[base + (size_t)k * DH + dcol];
        vt[k][dcol] = vbuf[base + (size_t)k * DH + dcol];
    }

    const int d0 = (t >> 4) * 4;
    const int e0 = (t & 15) * 4;

    for (int br = 0; br < 3; ++br) {
        __syncthreads();
        #pragma unroll
        for (int j = 0; j < 16; ++j) {
            const int k = rg + j;
            float f = 1.f;
            const float pos = (float)(c * CHUNK + k);
            if (br == 1) f = cosf(pos * w);
            else if (br == 2) f = sinf(pos * w);
            kf[k][dcol] = kpl[j] * f;
        }
        __syncthreads();

        float S[4][4] = {};
        float zr[4] = {};
        #pragma unroll 4
        for (int k = 0; k < CHUNK; ++k) {
            const float4 kv = *(const float4*)&kf[k][d0];
            const float4 ve = *(const float4*)&vt[k][e0];
            S[0][0] += kv.x * ve.x; S[0][1] += kv.x * ve.y;
            S[0][2] += kv.x * ve.z; S[0][3] += kv.x * ve.w;
            S[1][0] += kv.y * ve.x; S[1][1] += kv.y * ve.y;
            S[1][2] += kv.y * ve.z; S[1][3] += kv.y * ve.w;
            S[2][0] += kv.z * ve.x; S[2][1] += kv.z * ve.y;
            S[2][2] += kv.z * ve.z; S[2][3] += kv.z * ve.w;
            S[3][0] += kv.w * ve.x; S[3][1] += kv.w * ve.y;
            S[3][2] += kv.w * ve.z; S[3][3] += kv.w * ve.w;
            zr[0] += kv.x; zr[1] += kv.y; zr[2] += kv.z; zr[3] += kv.w;
        }

        float* Sg = Ssum + ((size_t)(br * NHTOT + nh) * NCHUNK + c) * (DH * DH);
        #pragma unroll
        for (int i = 0; i < 4; ++i) {
            float4 o;
            o.x = S[i][0]; o.y = S[i][1]; o.z = S[i][2]; o.w = S[i][3];
            *(float4*)&Sg[(d0 + i) * DH + e0] = o;
        }
        if ((t & 15) == 0) {
            float* zg = zsum + ((size_t)(br * NHTOT + nh) * NCHUNK + c) * DH;
            #pragma unroll
            for (int i = 0; i < 4; ++i) zg[d0 + i] = zr[i];
        }
    }
}

// ---------------------------------------------------------------------------
// Kernel B2: in-place exclusive prefix scan over the chunk axis.
// One block per (br,nh): sequential over 16 chunks, fully parallel in (d,e).
// ---------------------------------------------------------------------------
__global__ __launch_bounds__(256) void scan_kernel(
    float* __restrict__ Ssum,
    float* __restrict__ zsum)
{
    const int b = blockIdx.x;      // br*NHTOT + nh, 48 blocks
    const int t = threadIdx.x;

    float* S = Ssum + (size_t)b * NCHUNK * (DH * DH);
    float run[16];
    #pragma unroll
    for (int j = 0; j < 16; ++j) run[j] = 0.f;
    for (int c = 0; c < NCHUNK; ++c) {
        #pragma unroll
        for (int j = 0; j < 16; ++j) {
            const int idx = c * (DH * DH) + j * 256 + t;
            const float tmp = S[idx];
            S[idx] = run[j];
            run[j] += tmp;
        }
    }
    if (t < DH) {
        float* z = zsum + (size_t)b * NCHUNK * DH;
        float zr = 0.f;
        for (int c = 0; c < NCHUNK; ++c) {
            const int idx = c * DH + t;
            const float tmp = z[idx];
            z[idx] = zr;
            zr += tmp;
        }
    }
}

// ---------------------------------------------------------------------------
// Kernel C: per-(n,h,chunk) output; Ssum/zsum now hold exclusive prefixes.
// ---------------------------------------------------------------------------
__global__ __launch_bounds__(256) void attn_kernel(
    const float* __restrict__ qbuf,
    const float* __restrict__ kbuf,
    const float* __restrict__ vbuf,
    const float* __restrict__ Ssum,
    const float* __restrict__ zsum,
    const float* __restrict__ pw,
    const float* __restrict__ pb,
    float* __restrict__ outp)
{
    const int c  = blockIdx.x;
    const int nh = blockIdx.y;
    const int n  = nh >> 3;
    const int h  = nh & (NHEAD - 1);
    const int t  = threadIdx.x;

    __shared__ float Sb[DH][PAD];
    __shared__ float qT[DH][PAD];
    __shared__ float kT[DH][PAD];
    __shared__ float vt[CHUNK][PAD];
    __shared__ float At[CHUNK][PAD];
    __shared__ float zl[DH];
    __shared__ float dl[CHUNK];

    const int l0 = (t >> 4) * 4;
    const int e0 = (t & 15) * 4;

    const size_t base = ((size_t)nh * LSEQ + (size_t)c * CHUNK) * DH;
    const int dcol = t & 63;
    const int rg = (t >> 6) * 16;

    #pragma unroll
    for (int j = 0; j < 16; ++j) {
        const int k = rg + j;
        vt[k][dcol] = vbuf[base + (size_t)k * DH + dcol];
    }

    const float w = pw[h * DH + dcol];
    const float bias = 3.14159265358979323846f / (1.f + expf(-pb[h * DH + dcol]));

    float qpl[16], kpl[16];
    #pragma unroll
    for (int j = 0; j < 16; ++j) {
        const int l = rg + j;
        qpl[j] = qbuf[base + (size_t)l * DH + dcol];
        kpl[j] = kbuf[base + (size_t)l * DH + dcol];
    }

    float num[4][4] = {};
    float Ar[4][4] = {};
    float den[4] = {};

    for (int br = 0; br < 3; ++br) {
        // prefix state: single direct read (scanned)
        const float* Sg = Ssum + ((size_t)(br * NHTOT + nh) * NCHUNK + c) * (DH * DH);
        float sacc[16];
        #pragma unroll
        for (int j = 0; j < 16; ++j) sacc[j] = Sg[j * 256 + t];
        float zacc = 0.f;
        if (t < DH)
            zacc = zsum[((size_t)(br * NHTOT + nh) * NCHUNK + c) * DH + t];

        __syncthreads();   // previous branch's readers done before overwrite
        #pragma unroll
        for (int j = 0; j < 16; ++j) {
            const int f = j * 256 + t;
            Sb[f >> 6][f & 63] = sacc[j];
        }
        if (t < DH) zl[t] = zacc;

        #pragma unroll
        for (int j = 0; j < 16; ++j) {
            const int l = rg + j;
            const float pos = (float)(c * CHUNK + l);
            float tq = 1.f, tk = 1.f;
            if (br == 1) { tq = cosf(pos * w + bias); tk = cosf(pos * w); }
            else if (br == 2) { tq = sinf(pos * w + bias); tk = sinf(pos * w); }
            qT[dcol][l] = qpl[j] * tq;
            kT[dcol][l] = kpl[j] * tk;
        }
        __syncthreads();

        #pragma unroll 2
        for (int d = 0; d < DH; ++d) {
            const float4 qv = *(const float4*)&qT[d][l0];
            const float4 Sv = *(const float4*)&Sb[d][e0];
            const float4 kv = *(const float4*)&kT[d][e0];
            const float z = zl[d];
            num[0][0] += qv.x * Sv.x; num[0][1] += qv.x * Sv.y;
            num[0][2] += qv.x * Sv.z; num[0][3] += qv.x * Sv.w;
            num[1][0] += qv.y * Sv.x; num[1][1] += qv.y * Sv.y;
            num[1][2] += qv.y * Sv.z; num[1][3] += qv.y * Sv.w;
            num[2][0] += qv.z * Sv.x; num[2][1] += qv.z * Sv.y;
            num[2][2] += qv.z * Sv.z; num[2][3] += qv.z * Sv.w;
            num[3][0] += qv.w * Sv.x; num[3][1] += qv.w * Sv.y;
            num[3][2] += qv.w * Sv.z; num[3][3] += qv.w * Sv.w;
            Ar[0][0] += qv.x * kv.x; Ar[0][1] += qv.x * kv.y;
            Ar[0][2] += qv.x * kv.z; Ar[0][3] += qv.x * kv.w;
            Ar[1][0] += qv.y * kv.x; Ar[1][1] += qv.y * kv.y;
            Ar[1][2] += qv.y * kv.z; Ar[1][3] += qv.y * kv.w;
            Ar[2][0] += qv.z * kv.x; Ar[2][1] += qv.z * kv.y;
            Ar[2][2] += qv.z * kv.z; Ar[2][3] += qv.z * kv.w;
            Ar[3][0] += qv.w * kv.x; Ar[3][1] += qv.w * kv.y;
            Ar[3][2] += qv.w * kv.z; Ar[3][3] += qv.w * kv.w;
            den[0] += qv.x * z; den[1] += qv.y * z;
            den[2] += qv.z * z; den[3] += qv.w * z;
        }
    }

    #pragma unroll
    for (int i = 0; i < 4; ++i)
        #pragma unroll
        for (int j = 0; j < 4; ++j) {
            const int l = l0 + i, k = e0 + j;
            At[k][l] = (k <= l) ? Ar[i][j] : 0.f;
        }
    if ((t & 15) == 0) {
        #pragma unroll
        for (int i = 0; i < 4; ++i) dl[l0 + i] = den[i];
    }
    __syncthreads();

    if (t < DH) {
        float s = 0.f;
        for (int k = 0; k <= t; ++k) s += At[k][t];
        dl[t] += s;
    }
    __syncthreads();

    #pragma unroll 2
    for (int k = 0; k < CHUNK; ++k) {
        const float4 av = *(const float4*)&At[k][l0];
        const float4 vv = *(const float4*)&vt[k][e0];
        num[0][0] += av.x * vv.x; num[0][1] += av.x * vv.y;
        num[0][2] += av.x * vv.z; num[0][3] += av.x * vv.w;
        num[1][0] += av.y * vv.x; num[1][1] += av.y * vv.y;
        num[1][2] += av.y * vv.z; num[1][3] += av.y * vv.w;
        num[2][0] += av.z * vv.x; num[2][1] += av.z * vv.y;
        num[2][2] += av.z * vv.z; num[2][3] += av.z * vv.w;
        num[3][0] += av.w * vv.x; num[3][1] += av.w * vv.y;
        num[3][2] += av.w * vv.z; num[3][3] += av.w * vv.w;
    }

    #pragma unroll
    for (int i = 0; i < 4; ++i) {
        const int l = c * CHUNK + l0 + i;
        const float inv = 1.f / dl[l0 + i];
        const size_t off = ((size_t)n * LSEQ + l) * DIM + h * DH + e0;
        float4 o;
        o.x = num[i][0] * inv; o.y = num[i][1] * inv;
        o.z = num[i][2] * inv; o.w = num[i][3] * inv;
        *(float4*)&outp[off] = o;
    }
}

extern "C" void kernel_launch(void* const* d_in, const int* in_sizes, int n_in,
                              void* d_out, int out_size, void* d_ws, size_t ws_size,
                              hipStream_t stream) {
    const float* query = (const float*)d_in[0];
    const float* key   = (const float*)d_in[1];
    const float* Wq    = (const float*)d_in[2];
    const float* Wk    = (const float*)d_in[3];
    const float* Wv    = (const float*)d_in[4];
    const float* pw    = (const float*)d_in[5];
    const float* pb    = (const float*)d_in[6];

    float* ws = (float*)d_ws;
    float* qbuf = ws;
    float* kbuf = ws + 1048576;
    float* vbuf = ws + 2097152;
    float* Ssum = ws + 3145728;
    float* zsum = ws + 6291456;   // total 6,340,608 floats = 25.4 MB

    proj_kernel<<<dim3(16, 4, 3), 256, 0, stream>>>(
        query, key, Wq, Wk, Wv, qbuf, kbuf, vbuf);
    chunksum_kernel<<<dim3(NCHUNK, NHTOT), 256, 0, stream>>>(
        kbuf, vbuf, pw, Ssum, zsum);
    scan_kernel<<<dim3(3 * NHTOT), 256, 0, stream>>>(Ssum, zsum);
    attn_kernel<<<dim3(NCHUNK, NHTOT), 256, 0, stream>>>(
        qbuf, kbuf, vbuf, Ssum, zsum, pw, pb, (float*)d_out);
}

// Round 4
// 174.930 us; speedup vs baseline: 1.0469x; 1.0054x over previous
//
#include <hip/hip_runtime.h>
#include <hip/hip_bf16.h>

#define LSEQ   1024
#define NHEAD  8
#define DH     64
#define DIM    512
#define CHUNK  64
#define NCHUNK 16
#define NHTOT  16
#define PAD    68    // f32 LDS row pad
#define BK     64
#define LDK2   72    // bf16 LDS row stride: 144 B -> bank-balanced b128 r/w

typedef __attribute__((ext_vector_type(8))) short short8;
typedef __attribute__((ext_vector_type(4))) float floatx4;

__device__ __forceinline__ float softplusf_(float x) {
    if (x > 20.f) return x;
    return log1pf(expf(x));
}

__device__ __forceinline__ unsigned short bf16_rne(float x) {
    unsigned int u = __float_as_uint(x);
    u += 0x7FFFu + ((u >> 16) & 1u);
    return (unsigned short)(u >> 16);
}
__device__ __forceinline__ float bf16_tof(unsigned short h) {
    return __uint_as_float(((unsigned int)h) << 16);
}

// ---------------------------------------------------------------------------
// Kernel 0: f32 -> (hi,lo) bf16 split, elementwise.  x ~= hi + lo, rel ~2^-17.
// ---------------------------------------------------------------------------
struct CvtArgs {
    const float* src[5];
    unsigned short* hi[5];
    unsigned short* lo[5];
    int n4[5];
};

__global__ __launch_bounds__(256) void cvt_kernel(CvtArgs a) {
    const int seg = blockIdx.y;
    const int i = blockIdx.x * 256 + threadIdx.x;
    if (i >= a.n4[seg]) return;
    const float4 x = ((const float4*)a.src[seg])[i];
    ushort4 h, l;
    h.x = bf16_rne(x.x); l.x = bf16_rne(x.x - bf16_tof(h.x));
    h.y = bf16_rne(x.y); l.y = bf16_rne(x.y - bf16_tof(h.y));
    h.z = bf16_rne(x.z); l.z = bf16_rne(x.z - bf16_tof(h.z));
    h.w = bf16_rne(x.w); l.w = bf16_rne(x.w - bf16_tof(h.w));
    ((ushort4*)a.hi[seg])[i] = h;
    ((ushort4*)a.lo[seg])[i] = l;
}

// ---------------------------------------------------------------------------
// Kernel A: MFMA GEMM  C = X @ W^T  (both k-major), 3 bf16 passes hh+hl+lh.
// 128x128 tile, 4 waves (2x2 of 64x64), 16x16x32 bf16, BK=64, reg prefetch.
// Epilogue: softplus for q/k; store f32 [n*H+h][l][d].
// ---------------------------------------------------------------------------
__global__ __launch_bounds__(256) void proj_kernel(
    const unsigned short* __restrict__ Qhi, const unsigned short* __restrict__ Qlo,
    const unsigned short* __restrict__ Khi, const unsigned short* __restrict__ Klo,
    const unsigned short* __restrict__ Whi, const unsigned short* __restrict__ Wlo,
    float* __restrict__ qbuf, float* __restrict__ kbuf, float* __restrict__ vbuf)
{
    const int mt  = blockIdx.x;   // 16 tiles over M=2048
    const int ot  = blockIdx.y;   // 4 tiles over O=512
    const int sel = blockIdx.z;
    const int t   = threadIdx.x;

    const unsigned short* __restrict__ Xh = (sel == 0) ? Qhi : Khi;
    const unsigned short* __restrict__ Xl = (sel == 0) ? Qlo : Klo;
    const unsigned short* __restrict__ Wh = Whi + (size_t)sel * DIM * DIM;
    const unsigned short* __restrict__ Wl = Wlo + (size_t)sel * DIM * DIM;
    float* __restrict__ obuf = (sel == 0) ? qbuf : (sel == 1) ? kbuf : vbuf;

    __shared__ short AhL[128 * LDK2];
    __shared__ short AlL[128 * LDK2];
    __shared__ short BhL[128 * LDK2];
    __shared__ short BlL[128 * LDK2];

    const int m0 = mt * 128, o0 = ot * 128;
    const int lane = t & 63, wave = t >> 6;
    const int quad = lane >> 4, l16 = lane & 15;
    const int wm = wave >> 1, wn = wave & 1;

    int srow[4], sg8[4];   // staging slots: 1024 = 128 rows x 8 chunks(8 bf16)
    #pragma unroll
    for (int i = 0; i < 4; ++i) {
        const int slot = i * 256 + t;
        srow[i] = slot >> 3;
        sg8[i]  = (slot & 7) * 8;
    }

    floatx4 acc[4][4];
    #pragma unroll
    for (int i = 0; i < 4; ++i)
        #pragma unroll
        for (int j = 0; j < 4; ++j) acc[i][j] = (floatx4){0.f, 0.f, 0.f, 0.f};

    short8 pah[4], pal[4], pbh[4], pbl[4];
    #pragma unroll
    for (int i = 0; i < 4; ++i) {
        const size_t га = (size_t)(m0 + srow[i]) * DIM + sg8[i];
        const size_t gb = (size_t)(o0 + srow[i]) * DIM + sg8[i];
        pah[i] = *(const short8*)&Xh[га]; pal[i] = *(const short8*)&Xl[га];
        pbh[i] = *(const short8*)&Wh[gb]; pbl[i] = *(const short8*)&Wl[gb];
    }

    for (int kt = 0; kt < DIM; kt += BK) {
        __syncthreads();   // prior iter's fragment reads done
        #pragma unroll
        for (int i = 0; i < 4; ++i) {
            const int lo_ = srow[i] * LDK2 + sg8[i];
            *(short8*)&AhL[lo_] = pah[i];
            *(short8*)&AlL[lo_] = pal[i];
            *(short8*)&BhL[lo_] = pbh[i];
            *(short8*)&BlL[lo_] = pbl[i];
        }
        __syncthreads();

        if (kt + BK < DIM) {
            #pragma unroll
            for (int i = 0; i < 4; ++i) {
                const size_t ga = (size_t)(m0 + srow[i]) * DIM + kt + BK + sg8[i];
                const size_t gb = (size_t)(o0 + srow[i]) * DIM + kt + BK + sg8[i];
                pah[i] = *(const short8*)&Xh[ga]; pal[i] = *(const short8*)&Xl[ga];
                pbh[i] = *(const short8*)&Wh[gb]; pbl[i] = *(const short8*)&Wl[gb];
            }
        }

        #pragma unroll
        for (int s = 0; s < 2; ++s) {
            short8 ah[4], al[4];
            #pragma unroll
            for (int mi = 0; mi < 4; ++mi) {
                const int off = (wm * 64 + mi * 16 + l16) * LDK2 + s * 32 + quad * 8;
                ah[mi] = *(const short8*)&AhL[off];
                al[mi] = *(const short8*)&AlL[off];
            }
            #pragma unroll
            for (int ni = 0; ni < 4; ++ni) {
                const int off = (wn * 64 + ni * 16 + l16) * LDK2 + s * 32 + quad * 8;
                const short8 bh = *(const short8*)&BhL[off];
                const short8 bl = *(const short8*)&BlL[off];
                #pragma unroll
                for (int mi = 0; mi < 4; ++mi) {
                    acc[mi][ni] = __builtin_amdgcn_mfma_f32_16x16x32_bf16(ah[mi], bh, acc[mi][ni], 0, 0, 0);
                    acc[mi][ni] = __builtin_amdgcn_mfma_f32_16x16x32_bf16(ah[mi], bl, acc[mi][ni], 0, 0, 0);
                    acc[mi][ni] = __builtin_amdgcn_mfma_f32_16x16x32_bf16(al[mi], bh, acc[mi][ni], 0, 0, 0);
                }
            }
        }
    }

    // C/D layout: col = lane&15, row = quad*4 + reg
    #pragma unroll
    for (int mi = 0; mi < 4; ++mi)
        #pragma unroll
        for (int ni = 0; ni < 4; ++ni) {
            const int o = o0 + wn * 64 + ni * 16 + l16;
            const int h = o >> 6, d = o & (DH - 1);
            #pragma unroll
            for (int r = 0; r < 4; ++r) {
                const int m = m0 + wm * 64 + mi * 16 + quad * 4 + r;
                const int n = m >> 10, l = m & (LSEQ - 1);
                float val = acc[mi][ni][r];
                if (sel < 2) val = softplusf_(val);
                obuf[(((size_t)(n * NHEAD + h)) * LSEQ + l) * DH + d] = val;
            }
        }
}

// ---------------------------------------------------------------------------
// Kernel B: per-(c,nh,br) chunk sums  S[d][e] = sum_k kf[k][d] v[k][e], z[d].
// ---------------------------------------------------------------------------
__global__ __launch_bounds__(256) void chunksum_kernel(
    const float* __restrict__ kbuf, const float* __restrict__ vbuf,
    const float* __restrict__ pw,
    float* __restrict__ Ssum, float* __restrict__ zsum)
{
    const int c  = blockIdx.x;
    const int nh = blockIdx.y;
    const int br = blockIdx.z;
    const int h  = nh & (NHEAD - 1);
    const int t  = threadIdx.x;

    __shared__ float kf[CHUNK][PAD];
    __shared__ float vt[CHUNK][PAD];

    const size_t base = ((size_t)nh * LSEQ + (size_t)c * CHUNK) * DH;
    const int dcol = t & 63;
    const int rg = (t >> 6) * 16;
    const float w = pw[h * DH + dcol];

    #pragma unroll
    for (int j = 0; j < 16; ++j) {
        const int k = rg + j;
        const float kv = kbuf[base + (size_t)k * DH + dcol];
        vt[k][dcol] = vbuf[base + (size_t)k * DH + dcol];
        float f = 1.f;
        const float pos = (float)(c * CHUNK + k);
        if (br == 1) f = cosf(pos * w);
        else if (br == 2) f = sinf(pos * w);
        kf[k][dcol] = kv * f;
    }
    __syncthreads();

    const int d0 = (t >> 4) * 4;
    const int e0 = (t & 15) * 4;

    float S[4][4] = {};
    float zr[4] = {};
    #pragma unroll 4
    for (int k = 0; k < CHUNK; ++k) {
        const float4 kv = *(const float4*)&kf[k][d0];
        const float4 ve = *(const float4*)&vt[k][e0];
        S[0][0] += kv.x * ve.x; S[0][1] += kv.x * ve.y;
        S[0][2] += kv.x * ve.z; S[0][3] += kv.x * ve.w;
        S[1][0] += kv.y * ve.x; S[1][1] += kv.y * ve.y;
        S[1][2] += kv.y * ve.z; S[1][3] += kv.y * ve.w;
        S[2][0] += kv.z * ve.x; S[2][1] += kv.z * ve.y;
        S[2][2] += kv.z * ve.z; S[2][3] += kv.z * ve.w;
        S[3][0] += kv.w * ve.x; S[3][1] += kv.w * ve.y;
        S[3][2] += kv.w * ve.z; S[3][3] += kv.w * ve.w;
        zr[0] += kv.x; zr[1] += kv.y; zr[2] += kv.z; zr[3] += kv.w;
    }

    float* Sg = Ssum + ((size_t)(br * NHTOT + nh) * NCHUNK + c) * (DH * DH);
    #pragma unroll
    for (int i = 0; i < 4; ++i) {
        float4 o;
        o.x = S[i][0]; o.y = S[i][1]; o.z = S[i][2]; o.w = S[i][3];
        *(float4*)&Sg[(d0 + i) * DH + e0] = o;
    }
    if ((t & 15) == 0) {
        float* zg = zsum + ((size_t)(br * NHTOT + nh) * NCHUNK + c) * DH;
        #pragma unroll
        for (int i = 0; i < 4; ++i) zg[d0 + i] = zr[i];
    }
}

// ---------------------------------------------------------------------------
// Kernel B2: in-place exclusive prefix scan over chunks, per (br,nh).
// ---------------------------------------------------------------------------
__global__ __launch_bounds__(256) void scan_kernel(
    float* __restrict__ Ssum, float* __restrict__ zsum)
{
    const int b = blockIdx.x;   // 48
    const int t = threadIdx.x;

    float* S = Ssum + (size_t)b * NCHUNK * (DH * DH);
    float run[16];
    #pragma unroll
    for (int j = 0; j < 16; ++j) run[j] = 0.f;
    for (int c = 0; c < NCHUNK; ++c) {
        #pragma unroll
        for (int j = 0; j < 16; ++j) {
            const int idx = c * (DH * DH) + j * 256 + t;
            const float tmp = S[idx];
            S[idx] = run[j];
            run[j] += tmp;
        }
    }
    if (t < DH) {
        float* z = zsum + (size_t)b * NCHUNK * DH;
        float zr = 0.f;
        for (int c = 0; c < NCHUNK; ++c) {
            const int idx = c * DH + t;
            const float tmp = z[idx];
            z[idx] = zr;
            zr += tmp;
        }
    }
}

// ---------------------------------------------------------------------------
// Kernel C: per-(c,nh,br) partial num/den (prefix + intra-chunk causal).
// S-prefix and v are read straight from global (L2); LDS ~53 KB -> 3 blk/CU.
// ---------------------------------------------------------------------------
__global__ __launch_bounds__(256) void attn_kernel(
    const float* __restrict__ qbuf, const float* __restrict__ kbuf,
    const float* __restrict__ vbuf,
    const float* __restrict__ Ssum, const float* __restrict__ zsum,
    const float* __restrict__ pw, const float* __restrict__ pb,
    float* __restrict__ numP, float* __restrict__ denP)
{
    const int c  = blockIdx.x;
    const int nh = blockIdx.y;
    const int br = blockIdx.z;
    const int n  = nh >> 3;
    const int h  = nh & (NHEAD - 1);
    const int t  = threadIdx.x;

    __shared__ float qT[DH][PAD];     // qf^T [d][l]
    __shared__ float kT[DH][PAD];     // kf^T [d][k]
    __shared__ float At[CHUNK][PAD];  // masked scores^T [k][l]
    __shared__ float zl[DH];
    __shared__ float dl[CHUNK];
    __shared__ float dpart[4][CHUNK];

    const int l0 = (t >> 4) * 4;
    const int e0 = (t & 15) * 4;
    const size_t base = ((size_t)nh * LSEQ + (size_t)c * CHUNK) * DH;
    const int dcol = t & 63;
    const int rg = (t >> 6) * 16;

    const float w = pw[h * DH + dcol];
    const float bias = 3.14159265358979323846f / (1.f + expf(-pb[h * DH + dcol]));

    #pragma unroll
    for (int j = 0; j < 16; ++j) {
        const int l = rg + j;
        const float q = qbuf[base + (size_t)l * DH + dcol];
        const float k = kbuf[base + (size_t)l * DH + dcol];
        const float pos = (float)(c * CHUNK + l);
        float tq = 1.f, tk = 1.f;
        if (br == 1) { tq = cosf(pos * w + bias); tk = cosf(pos * w); }
        else if (br == 2) { tq = sinf(pos * w + bias); tk = sinf(pos * w); }
        qT[dcol][l] = q * tq;
        kT[dcol][l] = k * tk;
    }
    if (t < DH)
        zl[t] = zsum[((size_t)(br * NHTOT + nh) * NCHUNK + c) * DH + t];
    __syncthreads();

    const float* Sg = Ssum + ((size_t)(br * NHTOT + nh) * NCHUNK + c) * (DH * DH);

    float num[4][4] = {};
    float Ar[4][4] = {};
    float den[4] = {};

    #pragma unroll 2
    for (int d = 0; d < DH; ++d) {
        const float4 qv = *(const float4*)&qT[d][l0];
        const float4 kv = *(const float4*)&kT[d][e0];
        const float4 Sv = *(const float4*)&Sg[d * DH + e0];
        const float z = zl[d];
        num[0][0] += qv.x * Sv.x; num[0][1] += qv.x * Sv.y;
        num[0][2] += qv.x * Sv.z; num[0][3] += qv.x * Sv.w;
        num[1][0] += qv.y * Sv.x; num[1][1] += qv.y * Sv.y;
        num[1][2] += qv.y * Sv.z; num[1][3] += qv.y * Sv.w;
        num[2][0] += qv.z * Sv.x; num[2][1] += qv.z * Sv.y;
        num[2][2] += qv.z * Sv.z; num[2][3] += qv.z * Sv.w;
        num[3][0] += qv.w * Sv.x; num[3][1] += qv.w * Sv.y;
        num[3][2] += qv.w * Sv.z; num[3][3] += qv.w * Sv.w;
        Ar[0][0] += qv.x * kv.x; Ar[0][1] += qv.x * kv.y;
        Ar[0][2] += qv.x * kv.z; Ar[0][3] += qv.x * kv.w;
        Ar[1][0] += qv.y * kv.x; Ar[1][1] += qv.y * kv.y;
        Ar[1][2] += qv.y * kv.z; Ar[1][3] += qv.y * kv.w;
        Ar[2][0] += qv.z * kv.x; Ar[2][1] += qv.z * kv.y;
        Ar[2][2] += qv.z * kv.z; Ar[2][3] += qv.z * kv.w;
        Ar[3][0] += qv.w * kv.x; Ar[3][1] += qv.w * kv.y;
        Ar[3][2] += qv.w * kv.z; Ar[3][3] += qv.w * kv.w;
        den[0] += qv.x * z; den[1] += qv.y * z;
        den[2] += qv.z * z; den[3] += qv.w * z;
    }

    #pragma unroll
    for (int i = 0; i < 4; ++i)
        #pragma unroll
        for (int j = 0; j < 4; ++j) {
            const int l = l0 + i, k = e0 + j;
            At[k][l] = (k <= l) ? Ar[i][j] : 0.f;
        }
    if ((t & 15) == 0) {
        #pragma unroll
        for (int i = 0; i < 4; ++i) dl[l0 + i] = den[i];
    }
    __syncthreads();

    {   // parallel column sums of masked At (zeros above diagonal)
        const int col = t & 63, seg = t >> 6;
        float s = 0.f;
        #pragma unroll
        for (int j = 0; j < 16; ++j) s += At[seg * 16 + j][col];
        dpart[seg][col] = s;
    }
    __syncthreads();
    if (t < DH) dl[t] += dpart[0][t] + dpart[1][t] + dpart[2][t] + dpart[3][t];
    __syncthreads();

    #pragma unroll 2
    for (int k = 0; k < CHUNK; ++k) {
        const float4 av = *(const float4*)&At[k][l0];
        const float4 vv = *(const float4*)&vbuf[base + (size_t)k * DH + e0];
        num[0][0] += av.x * vv.x; num[0][1] += av.x * vv.y;
        num[0][2] += av.x * vv.z; num[0][3] += av.x * vv.w;
        num[1][0] += av.y * vv.x; num[1][1] += av.y * vv.y;
        num[1][2] += av.y * vv.z; num[1][3] += av.y * vv.w;
        num[2][0] += av.z * vv.x; num[2][1] += av.z * vv.y;
        num[2][2] += av.z * vv.z; num[2][3] += av.z * vv.w;
        num[3][0] += av.w * vv.x; num[3][1] += av.w * vv.y;
        num[3][2] += av.w * vv.z; num[3][3] += av.w * vv.w;
    }

    #pragma unroll
    for (int i = 0; i < 4; ++i) {
        const int l = c * CHUNK + l0 + i;
        float4 o;
        o.x = num[i][0]; o.y = num[i][1]; o.z = num[i][2]; o.w = num[i][3];
        *(float4*)&numP[(((size_t)br * 2 + n) * LSEQ + l) * DIM + h * DH + e0] = o;
    }
    if ((t & 15) == 0) {
        #pragma unroll
        for (int i = 0; i < 4; ++i)
            denP[((size_t)(br * NHTOT + nh)) * LSEQ + c * CHUNK + l0 + i] = dl[l0 + i];
    }
}

// ---------------------------------------------------------------------------
// Kernel D: out = (num0+num1+num2) / (den0+den1+den2), elementwise float4.
// ---------------------------------------------------------------------------
__global__ __launch_bounds__(256) void combine_kernel(
    const float* __restrict__ numP, const float* __restrict__ denP,
    float* __restrict__ outp)
{
    const int i = blockIdx.x * 256 + threadIdx.x;   // float4 index, 262144 total
    const int row = i >> 7;           // n*LSEQ + l
    const int ci  = i & 127;
    const int n = row >> 10, l = row & (LSEQ - 1), h = ci >> 4;
    const int nh = n * NHEAD + h;
    const float4* N = (const float4*)numP;
    const float4 a = N[i];
    const float4 b = N[i + 262144];
    const float4 cc = N[i + 524288];
    const float ds = denP[(size_t)nh * LSEQ + l]
                   + denP[((size_t)NHTOT + nh) * LSEQ + l]
                   + denP[((size_t)2 * NHTOT + nh) * LSEQ + l];
    const float inv = 1.f / ds;
    float4 o;
    o.x = (a.x + b.x + cc.x) * inv;
    o.y = (a.y + b.y + cc.y) * inv;
    o.z = (a.z + b.z + cc.z) * inv;
    o.w = (a.w + b.w + cc.w) * inv;
    ((float4*)outp)[i] = o;
}

extern "C" void kernel_launch(void* const* d_in, const int* in_sizes, int n_in,
                              void* d_out, int out_size, void* d_ws, size_t ws_size,
                              hipStream_t stream) {
    const float* query = (const float*)d_in[0];
    const float* key   = (const float*)d_in[1];
    const float* Wq    = (const float*)d_in[2];
    const float* Wk    = (const float*)d_in[3];
    const float* Wv    = (const float*)d_in[4];
    const float* pw    = (const float*)d_in[5];
    const float* pb    = (const float*)d_in[6];

    // Workspace layout. The bf16 hi/lo arrays (11.0 MB) live inside the numP
    // region (12.6 MB): cvt+proj consume them before attn writes numP.
    float* F = (float*)d_ws;
    unsigned short* U = (unsigned short*)d_ws;
    unsigned short* Qhi = U;
    unsigned short* Qlo = U + 1048576;
    unsigned short* Khi = U + 2097152;
    unsigned short* Klo = U + 3145728;
    unsigned short* Whi = U + 4194304;   // 3 x 262144
    unsigned short* Wlo = U + 4980736;   // ends at 11.53 MB
    float* numP = F;                     // 3,145,728 floats = 12.58 MB
    float* qbuf = F + 3145728;
    float* kbuf = F + 4194304;
    float* vbuf = F + 5242880;
    float* Ssum = F + 6291456;           // 3,145,728 floats
    float* zsum = F + 9437184;           // 49,152
    float* denP = F + 9486336;           // 49,152 -> total 38.1 MB

    CvtArgs ca;
    ca.src[0] = query; ca.hi[0] = Qhi; ca.lo[0] = Qlo; ca.n4[0] = 262144;
    ca.src[1] = key;   ca.hi[1] = Khi; ca.lo[1] = Klo; ca.n4[1] = 262144;
    ca.src[2] = Wq;    ca.hi[2] = Whi;            ca.lo[2] = Wlo;            ca.n4[2] = 65536;
    ca.src[3] = Wk;    ca.hi[3] = Whi + 262144;   ca.lo[3] = Wlo + 262144;   ca.n4[3] = 65536;
    ca.src[4] = Wv;    ca.hi[4] = Whi + 524288;   ca.lo[4] = Wlo + 524288;   ca.n4[4] = 65536;

    cvt_kernel<<<dim3(1024, 5), 256, 0, stream>>>(ca);
    proj_kernel<<<dim3(16, 4, 3), 256, 0, stream>>>(
        Qhi, Qlo, Khi, Klo, Whi, Wlo, qbuf, kbuf, vbuf);
    chunksum_kernel<<<dim3(NCHUNK, NHTOT, 3), 256, 0, stream>>>(
        kbuf, vbuf, pw, Ssum, zsum);
    scan_kernel<<<dim3(3 * NHTOT), 256, 0, stream>>>(Ssum, zsum);
    attn_kernel<<<dim3(NCHUNK, NHTOT, 3), 256, 0, stream>>>(
        qbuf, kbuf, vbuf, Ssum, zsum, pw, pb, numP, denP);
    combine_kernel<<<dim3(1024), 256, 0, stream>>>(numP, denP, (float*)d_out);
}

// Round 5
// 145.108 us; speedup vs baseline: 1.2620x; 1.2055x over previous
//
#include <hip/hip_runtime.h>
#include <hip/hip_bf16.h>

#define LSEQ   1024
#define NHEAD  8
#define DH     64
#define DIM    512
#define CHUNK  64
#define NCHUNK 16
#define NHTOT  16
#define PAD    68    // f32 LDS row pad
#define LDB    68    // ushort LDS row stride for proj (136 B -> uniform banks)

typedef __attribute__((ext_vector_type(8))) short short8;
typedef __attribute__((ext_vector_type(4))) float floatx4;

__device__ __forceinline__ float softplusf_(float x) {
    if (x > 20.f) return x;
    return log1pf(expf(x));
}
__device__ __forceinline__ unsigned short bf16_rne(float x) {
    unsigned int u = __float_as_uint(x);
    u += 0x7FFFu + ((u >> 16) & 1u);
    return (unsigned short)(u >> 16);
}

// ---------------------------------------------------------------------------
// Kernel A: C = X @ W^T, single-pass bf16 MFMA (error ~3e-3, threshold 6.6e-2).
// 64x64 tile / block, grid (32,8,3) = 768 blocks (~3 blocks/CU).
// 4 waves, each 32x32 (2x2 of 16x16x32). f32->bf16 rne folded into staging.
// Epilogue: softplus for q/k; store f32 [n*H+h][l][d].
// ---------------------------------------------------------------------------
__global__ __launch_bounds__(256) void proj_kernel(
    const float* __restrict__ query, const float* __restrict__ key,
    const float* __restrict__ Wq, const float* __restrict__ Wk,
    const float* __restrict__ Wv,
    float* __restrict__ qbuf, float* __restrict__ kbuf, float* __restrict__ vbuf)
{
    const int mt  = blockIdx.x;   // 32 tiles over M=2048
    const int ot  = blockIdx.y;   // 8 tiles over O=512
    const int sel = blockIdx.z;
    const int t   = threadIdx.x;

    const float* __restrict__ X = (sel == 0) ? query : key;
    const float* __restrict__ W = (sel == 0) ? Wq : (sel == 1) ? Wk : Wv;
    float* __restrict__ obuf = (sel == 0) ? qbuf : (sel == 1) ? kbuf : vbuf;

    __shared__ unsigned short As[64 * LDB];
    __shared__ unsigned short Bs[64 * LDB];

    const int m0 = mt * 64, o0 = ot * 64;
    const int lane = t & 63, wave = t >> 6;
    const int quad = lane >> 4, l16 = lane & 15;
    const int wm = wave >> 1, wn = wave & 1;

    const int srow = t >> 2;          // staging: 4 threads per row
    const int sc16 = (t & 3) * 16;    // 16 contiguous k-elems per thread

    floatx4 acc[2][2];
    #pragma unroll
    for (int i = 0; i < 2; ++i)
        #pragma unroll
        for (int j = 0; j < 2; ++j) acc[i][j] = (floatx4){0.f, 0.f, 0.f, 0.f};

    float4 ax[4], bx4[4];
    #pragma unroll
    for (int i = 0; i < 4; ++i) {
        ax[i]  = *(const float4*)&X[(size_t)(m0 + srow) * DIM + sc16 + i * 4];
        bx4[i] = *(const float4*)&W[(size_t)(o0 + srow) * DIM + sc16 + i * 4];
    }

    for (int kt = 0; kt < DIM; kt += 64) {
        __syncthreads();   // prior iter's fragment reads done
        {
            short8 a0, a1, b0, b1;
            #pragma unroll
            for (int i = 0; i < 2; ++i) {
                const float va[4] = {ax[i].x, ax[i].y, ax[i].z, ax[i].w};
                const float vb[4] = {bx4[i].x, bx4[i].y, bx4[i].z, bx4[i].w};
                #pragma unroll
                for (int j = 0; j < 4; ++j) {
                    a0[i * 4 + j] = (short)bf16_rne(va[j]);
                    b0[i * 4 + j] = (short)bf16_rne(vb[j]);
                }
            }
            #pragma unroll
            for (int i = 2; i < 4; ++i) {
                const float va[4] = {ax[i].x, ax[i].y, ax[i].z, ax[i].w};
                const float vb[4] = {bx4[i].x, bx4[i].y, bx4[i].z, bx4[i].w};
                #pragma unroll
                for (int j = 0; j < 4; ++j) {
                    a1[(i - 2) * 4 + j] = (short)bf16_rne(va[j]);
                    b1[(i - 2) * 4 + j] = (short)bf16_rne(vb[j]);
                }
            }
            *(short8*)&As[srow * LDB + sc16]     = a0;
            *(short8*)&As[srow * LDB + sc16 + 8] = a1;
            *(short8*)&Bs[srow * LDB + sc16]     = b0;
            *(short8*)&Bs[srow * LDB + sc16 + 8] = b1;
        }
        __syncthreads();

        if (kt + 64 < DIM) {
            #pragma unroll
            for (int i = 0; i < 4; ++i) {
                ax[i]  = *(const float4*)&X[(size_t)(m0 + srow) * DIM + kt + 64 + sc16 + i * 4];
                bx4[i] = *(const float4*)&W[(size_t)(o0 + srow) * DIM + kt + 64 + sc16 + i * 4];
            }
        }

        #pragma unroll
        for (int s = 0; s < 2; ++s) {
            short8 af[2], bf[2];
            #pragma unroll
            for (int mi = 0; mi < 2; ++mi)
                af[mi] = *(const short8*)&As[(wm * 32 + mi * 16 + l16) * LDB + s * 32 + quad * 8];
            #pragma unroll
            for (int ni = 0; ni < 2; ++ni)
                bf[ni] = *(const short8*)&Bs[(wn * 32 + ni * 16 + l16) * LDB + s * 32 + quad * 8];
            #pragma unroll
            for (int ni = 0; ni < 2; ++ni)
                #pragma unroll
                for (int mi = 0; mi < 2; ++mi)
                    acc[mi][ni] = __builtin_amdgcn_mfma_f32_16x16x32_bf16(af[mi], bf[ni], acc[mi][ni], 0, 0, 0);
        }
    }

    // C/D layout: col = lane&15, row = quad*4 + reg
    const int h = ot;   // o0 = ot*64 aligned to DH
    #pragma unroll
    for (int mi = 0; mi < 2; ++mi)
        #pragma unroll
        for (int ni = 0; ni < 2; ++ni) {
            const int d = wn * 32 + ni * 16 + l16;
            #pragma unroll
            for (int r = 0; r < 4; ++r) {
                const int m = m0 + wm * 32 + mi * 16 + quad * 4 + r;
                const int n = m >> 10, l = m & (LSEQ - 1);
                float val = acc[mi][ni][r];
                if (sel < 2) val = softplusf_(val);
                obuf[(((size_t)(n * NHEAD + h)) * LSEQ + l) * DH + d] = val;
            }
        }
}

// ---------------------------------------------------------------------------
// Kernel B: per-(c,nh,br) chunk sums  S[d][e] = sum_k kf[k][d] v[k][e], z[d].
// ---------------------------------------------------------------------------
__global__ __launch_bounds__(256) void chunksum_kernel(
    const float* __restrict__ kbuf, const float* __restrict__ vbuf,
    const float* __restrict__ pw,
    float* __restrict__ Ssum, float* __restrict__ zsum)
{
    const int c  = blockIdx.x;
    const int nh = blockIdx.y;
    const int br = blockIdx.z;
    const int h  = nh & (NHEAD - 1);
    const int t  = threadIdx.x;

    __shared__ float kf[CHUNK][PAD];
    __shared__ float vt[CHUNK][PAD];

    const size_t base = ((size_t)nh * LSEQ + (size_t)c * CHUNK) * DH;

    #pragma unroll
    for (int i = 0; i < 4; ++i) {
        const int e4 = i * 256 + t;
        const int k  = e4 >> 4;
        const int c4 = (e4 & 15) * 4;
        const float4 kv = *(const float4*)&kbuf[base + (size_t)k * DH + c4];
        const float4 vv = *(const float4*)&vbuf[base + (size_t)k * DH + c4];
        const float4 wv = *(const float4*)&pw[h * DH + c4];
        const float pos = (float)(c * CHUNK + k);
        float4 f;
        if (br == 0)      { f.x = 1.f; f.y = 1.f; f.z = 1.f; f.w = 1.f; }
        else if (br == 1) { f.x = cosf(pos * wv.x); f.y = cosf(pos * wv.y);
                            f.z = cosf(pos * wv.z); f.w = cosf(pos * wv.w); }
        else              { f.x = sinf(pos * wv.x); f.y = sinf(pos * wv.y);
                            f.z = sinf(pos * wv.z); f.w = sinf(pos * wv.w); }
        float4 ko;
        ko.x = kv.x * f.x; ko.y = kv.y * f.y; ko.z = kv.z * f.z; ko.w = kv.w * f.w;
        *(float4*)&kf[k][c4] = ko;
        *(float4*)&vt[k][c4] = vv;
    }
    __syncthreads();

    const int d0 = (t >> 4) * 4;
    const int e0 = (t & 15) * 4;

    float S[4][4] = {};
    float zr[4] = {};
    #pragma unroll 4
    for (int k = 0; k < CHUNK; ++k) {
        const float4 kv = *(const float4*)&kf[k][d0];
        const float4 ve = *(const float4*)&vt[k][e0];
        S[0][0] += kv.x * ve.x; S[0][1] += kv.x * ve.y;
        S[0][2] += kv.x * ve.z; S[0][3] += kv.x * ve.w;
        S[1][0] += kv.y * ve.x; S[1][1] += kv.y * ve.y;
        S[1][2] += kv.y * ve.z; S[1][3] += kv.y * ve.w;
        S[2][0] += kv.z * ve.x; S[2][1] += kv.z * ve.y;
        S[2][2] += kv.z * ve.z; S[2][3] += kv.z * ve.w;
        S[3][0] += kv.w * ve.x; S[3][1] += kv.w * ve.y;
        S[3][2] += kv.w * ve.z; S[3][3] += kv.w * ve.w;
        zr[0] += kv.x; zr[1] += kv.y; zr[2] += kv.z; zr[3] += kv.w;
    }

    float* Sg = Ssum + ((size_t)(br * NHTOT + nh) * NCHUNK + c) * (DH * DH);
    #pragma unroll
    for (int i = 0; i < 4; ++i) {
        float4 o;
        o.x = S[i][0]; o.y = S[i][1]; o.z = S[i][2]; o.w = S[i][3];
        *(float4*)&Sg[(d0 + i) * DH + e0] = o;
    }
    if ((t & 15) == 0) {
        float* zg = zsum + ((size_t)(br * NHTOT + nh) * NCHUNK + c) * DH;
        #pragma unroll
        for (int i = 0; i < 4; ++i) zg[d0 + i] = zr[i];
    }
}

// ---------------------------------------------------------------------------
// Kernel B2: in-place exclusive prefix over chunks; grid (48, 16) = 768 blocks.
// Loads all 16 chunk values upfront (independent), prefix in regs, stores.
// ---------------------------------------------------------------------------
__global__ __launch_bounds__(256) void scan_kernel(
    float* __restrict__ Ssum, float* __restrict__ zsum)
{
    const int b = blockIdx.x;     // br*NHTOT+nh
    const int s = blockIdx.y;     // 16 slices of 256 (d,e) slots
    const int idx = s * 256 + threadIdx.x;

    float* S = Ssum + (size_t)b * NCHUNK * (DH * DH);
    float v[NCHUNK];
    #pragma unroll
    for (int c = 0; c < NCHUNK; ++c) v[c] = S[c * (DH * DH) + idx];
    float run = 0.f;
    #pragma unroll
    for (int c = 0; c < NCHUNK; ++c) {
        const float nv = v[c];
        S[c * (DH * DH) + idx] = run;
        run += nv;
    }
    if (s == 0 && threadIdx.x < DH) {
        float* z = zsum + (size_t)b * NCHUNK * DH;
        float zv[NCHUNK];
        #pragma unroll
        for (int c = 0; c < NCHUNK; ++c) zv[c] = z[c * DH + threadIdx.x];
        float zr = 0.f;
        #pragma unroll
        for (int c = 0; c < NCHUNK; ++c) {
            const float nv = zv[c];
            z[c * DH + threadIdx.x] = zr;
            zr += nv;
        }
    }
}

// ---------------------------------------------------------------------------
// Kernel C: per-(c,nh) output, branches fused in-block (Ar/num/den accumulate
// across br in registers). Writes final out = num/den directly.
// ---------------------------------------------------------------------------
__global__ __launch_bounds__(256) void attn_kernel(
    const float* __restrict__ qbuf, const float* __restrict__ kbuf,
    const float* __restrict__ vbuf,
    const float* __restrict__ Ssum, const float* __restrict__ zsum,
    const float* __restrict__ pw, const float* __restrict__ pb,
    float* __restrict__ outp)
{
    const int c  = blockIdx.x;
    const int nh = blockIdx.y;
    const int n  = nh >> 3;
    const int h  = nh & (NHEAD - 1);
    const int t  = threadIdx.x;

    __shared__ float qT[DH][PAD];
    __shared__ float kT[DH][PAD];
    __shared__ float At[CHUNK][PAD];
    __shared__ float zl[DH];
    __shared__ float dl[CHUNK];
    __shared__ float dpart[4][CHUNK];

    const int l0 = (t >> 4) * 4;
    const int e0 = (t & 15) * 4;
    const size_t base = ((size_t)nh * LSEQ + (size_t)c * CHUNK) * DH;
    const int dcol = t & 63;
    const int rg = (t >> 6) * 16;

    const float w = pw[h * DH + dcol];
    const float bias = 3.14159265358979323846f / (1.f + expf(-pb[h * DH + dcol]));

    float qpl[16], kpl[16];
    #pragma unroll
    for (int j = 0; j < 16; ++j) {
        const int l = rg + j;
        qpl[j] = qbuf[base + (size_t)l * DH + dcol];
        kpl[j] = kbuf[base + (size_t)l * DH + dcol];
    }

    float num[4][4] = {};
    float Ar[4][4] = {};
    float den[4] = {};

    for (int br = 0; br < 3; ++br) {
        __syncthreads();   // previous branch's d-loop reads done
        #pragma unroll
        for (int j = 0; j < 16; ++j) {
            const int l = rg + j;
            const float pos = (float)(c * CHUNK + l);
            float tq = 1.f, tk = 1.f;
            if (br == 1) { tq = cosf(pos * w + bias); tk = cosf(pos * w); }
            else if (br == 2) { tq = sinf(pos * w + bias); tk = sinf(pos * w); }
            qT[dcol][l] = qpl[j] * tq;
            kT[dcol][l] = kpl[j] * tk;
        }
        if (t < DH)
            zl[t] = zsum[((size_t)(br * NHTOT + nh) * NCHUNK + c) * DH + t];
        __syncthreads();

        const float* Sg = Ssum + ((size_t)(br * NHTOT + nh) * NCHUNK + c) * (DH * DH);

        #pragma unroll 4
        for (int d = 0; d < DH; ++d) {
            const float4 qv = *(const float4*)&qT[d][l0];
            const float4 kv = *(const float4*)&kT[d][e0];
            const float4 Sv = *(const float4*)&Sg[d * DH + e0];
            const float z = zl[d];
            num[0][0] += qv.x * Sv.x; num[0][1] += qv.x * Sv.y;
            num[0][2] += qv.x * Sv.z; num[0][3] += qv.x * Sv.w;
            num[1][0] += qv.y * Sv.x; num[1][1] += qv.y * Sv.y;
            num[1][2] += qv.y * Sv.z; num[1][3] += qv.y * Sv.w;
            num[2][0] += qv.z * Sv.x; num[2][1] += qv.z * Sv.y;
            num[2][2] += qv.z * Sv.z; num[2][3] += qv.z * Sv.w;
            num[3][0] += qv.w * Sv.x; num[3][1] += qv.w * Sv.y;
            num[3][2] += qv.w * Sv.z; num[3][3] += qv.w * Sv.w;
            Ar[0][0] += qv.x * kv.x; Ar[0][1] += qv.x * kv.y;
            Ar[0][2] += qv.x * kv.z; Ar[0][3] += qv.x * kv.w;
            Ar[1][0] += qv.y * kv.x; Ar[1][1] += qv.y * kv.y;
            Ar[1][2] += qv.y * kv.z; Ar[1][3] += qv.y * kv.w;
            Ar[2][0] += qv.z * kv.x; Ar[2][1] += qv.z * kv.y;
            Ar[2][2] += qv.z * kv.z; Ar[2][3] += qv.z * kv.w;
            Ar[3][0] += qv.w * kv.x; Ar[3][1] += qv.w * kv.y;
            Ar[3][2] += qv.w * kv.z; Ar[3][3] += qv.w * kv.w;
            den[0] += qv.x * z; den[1] += qv.y * z;
            den[2] += qv.z * z; den[3] += qv.w * z;
        }
    }

    // causal mask (scores transposed) + den assembly
    #pragma unroll
    for (int i = 0; i < 4; ++i)
        #pragma unroll
        for (int j = 0; j < 4; ++j) {
            const int l = l0 + i, k = e0 + j;
            At[k][l] = (k <= l) ? Ar[i][j] : 0.f;
        }
    if ((t & 15) == 0) {
        #pragma unroll
        for (int i = 0; i < 4; ++i) dl[l0 + i] = den[i];
    }
    __syncthreads();

    {   // parallel column sums of masked At
        const int col = t & 63, seg = t >> 6;
        float s = 0.f;
        #pragma unroll
        for (int j = 0; j < 16; ++j) s += At[seg * 16 + j][col];
        dpart[seg][col] = s;
    }
    __syncthreads();
    if (t < DH) dl[t] += dpart[0][t] + dpart[1][t] + dpart[2][t] + dpart[3][t];
    __syncthreads();

    #pragma unroll 2
    for (int k = 0; k < CHUNK; ++k) {
        const float4 av = *(const float4*)&At[k][l0];
        const float4 vv = *(const float4*)&vbuf[base + (size_t)k * DH + e0];
        num[0][0] += av.x * vv.x; num[0][1] += av.x * vv.y;
        num[0][2] += av.x * vv.z; num[0][3] += av.x * vv.w;
        num[1][0] += av.y * vv.x; num[1][1] += av.y * vv.y;
        num[1][2] += av.y * vv.z; num[1][3] += av.y * vv.w;
        num[2][0] += av.z * vv.x; num[2][1] += av.z * vv.y;
        num[2][2] += av.z * vv.z; num[2][3] += av.z * vv.w;
        num[3][0] += av.w * vv.x; num[3][1] += av.w * vv.y;
        num[3][2] += av.w * vv.z; num[3][3] += av.w * vv.w;
    }

    #pragma unroll
    for (int i = 0; i < 4; ++i) {
        const int l = c * CHUNK + l0 + i;
        const float inv = 1.f / dl[l0 + i];
        const size_t off = ((size_t)n * LSEQ + l) * DIM + h * DH + e0;
        float4 o;
        o.x = num[i][0] * inv; o.y = num[i][1] * inv;
        o.z = num[i][2] * inv; o.w = num[i][3] * inv;
        *(float4*)&outp[off] = o;
    }
}

extern "C" void kernel_launch(void* const* d_in, const int* in_sizes, int n_in,
                              void* d_out, int out_size, void* d_ws, size_t ws_size,
                              hipStream_t stream) {
    const float* query = (const float*)d_in[0];
    const float* key   = (const float*)d_in[1];
    const float* Wq    = (const float*)d_in[2];
    const float* Wk    = (const float*)d_in[3];
    const float* Wv    = (const float*)d_in[4];
    const float* pw    = (const float*)d_in[5];
    const float* pb    = (const float*)d_in[6];

    float* F = (float*)d_ws;
    float* qbuf = F;                 // 1,048,576 floats
    float* kbuf = F + 1048576;
    float* vbuf = F + 2097152;
    float* Ssum = F + 3145728;       // 3,145,728 floats
    float* zsum = F + 6291456;       // 49,152 -> total 25.4 MB

    proj_kernel<<<dim3(32, 8, 3), 256, 0, stream>>>(
        query, key, Wq, Wk, Wv, qbuf, kbuf, vbuf);
    chunksum_kernel<<<dim3(NCHUNK, NHTOT, 3), 256, 0, stream>>>(
        kbuf, vbuf, pw, Ssum, zsum);
    scan_kernel<<<dim3(3 * NHTOT, NCHUNK), 256, 0, stream>>>(Ssum, zsum);
    attn_kernel<<<dim3(NCHUNK, NHTOT), 256, 0, stream>>>(
        qbuf, kbuf, vbuf, Ssum, zsum, pw, pb, (float*)d_out);
}

// Round 6
// 136.891 us; speedup vs baseline: 1.3378x; 1.0600x over previous
//
#include <hip/hip_runtime.h>
#include <hip/hip_bf16.h>

#define LSEQ   1024
#define NHEAD  8
#define DH     64
#define DIM    512
#define CHUNK  64
#define NCHUNK 16
#define NHTOT  16
#define PAD    68    // f32 LDS row pad
#define LDB    68    // ushort LDS row stride for proj (136 B -> uniform banks)

typedef __attribute__((ext_vector_type(8))) short short8;
typedef __attribute__((ext_vector_type(4))) float floatx4;

__device__ __forceinline__ float softplusf_(float x) {
    if (x > 20.f) return x;
    return log1pf(expf(x));
}
__device__ __forceinline__ unsigned short bf16_rne(float x) {
    unsigned int u = __float_as_uint(x);
    u += 0x7FFFu + ((u >> 16) & 1u);
    return (unsigned short)(u >> 16);
}

// ---------------------------------------------------------------------------
// Kernel A: C = X @ W^T, single-pass bf16 MFMA.  64x64 tile, grid (32,8,3).
// ---------------------------------------------------------------------------
__global__ __launch_bounds__(256) void proj_kernel(
    const float* __restrict__ query, const float* __restrict__ key,
    const float* __restrict__ Wq, const float* __restrict__ Wk,
    const float* __restrict__ Wv,
    float* __restrict__ qbuf, float* __restrict__ kbuf, float* __restrict__ vbuf)
{
    const int mt  = blockIdx.x;
    const int ot  = blockIdx.y;
    const int sel = blockIdx.z;
    const int t   = threadIdx.x;

    const float* __restrict__ X = (sel == 0) ? query : key;
    const float* __restrict__ W = (sel == 0) ? Wq : (sel == 1) ? Wk : Wv;
    float* __restrict__ obuf = (sel == 0) ? qbuf : (sel == 1) ? kbuf : vbuf;

    __shared__ unsigned short As[64 * LDB];
    __shared__ unsigned short Bs[64 * LDB];

    const int m0 = mt * 64, o0 = ot * 64;
    const int lane = t & 63, wave = t >> 6;
    const int quad = lane >> 4, l16 = lane & 15;
    const int wm = wave >> 1, wn = wave & 1;

    const int srow = t >> 2;
    const int sc16 = (t & 3) * 16;

    floatx4 acc[2][2];
    #pragma unroll
    for (int i = 0; i < 2; ++i)
        #pragma unroll
        for (int j = 0; j < 2; ++j) acc[i][j] = (floatx4){0.f, 0.f, 0.f, 0.f};

    float4 ax[4], bx4[4];
    #pragma unroll
    for (int i = 0; i < 4; ++i) {
        ax[i]  = *(const float4*)&X[(size_t)(m0 + srow) * DIM + sc16 + i * 4];
        bx4[i] = *(const float4*)&W[(size_t)(o0 + srow) * DIM + sc16 + i * 4];
    }

    for (int kt = 0; kt < DIM; kt += 64) {
        __syncthreads();
        {
            short8 a0, a1, b0, b1;
            #pragma unroll
            for (int i = 0; i < 2; ++i) {
                const float va[4] = {ax[i].x, ax[i].y, ax[i].z, ax[i].w};
                const float vb[4] = {bx4[i].x, bx4[i].y, bx4[i].z, bx4[i].w};
                #pragma unroll
                for (int j = 0; j < 4; ++j) {
                    a0[i * 4 + j] = (short)bf16_rne(va[j]);
                    b0[i * 4 + j] = (short)bf16_rne(vb[j]);
                }
            }
            #pragma unroll
            for (int i = 2; i < 4; ++i) {
                const float va[4] = {ax[i].x, ax[i].y, ax[i].z, ax[i].w};
                const float vb[4] = {bx4[i].x, bx4[i].y, bx4[i].z, bx4[i].w};
                #pragma unroll
                for (int j = 0; j < 4; ++j) {
                    a1[(i - 2) * 4 + j] = (short)bf16_rne(va[j]);
                    b1[(i - 2) * 4 + j] = (short)bf16_rne(vb[j]);
                }
            }
            *(short8*)&As[srow * LDB + sc16]     = a0;
            *(short8*)&As[srow * LDB + sc16 + 8] = a1;
            *(short8*)&Bs[srow * LDB + sc16]     = b0;
            *(short8*)&Bs[srow * LDB + sc16 + 8] = b1;
        }
        __syncthreads();

        if (kt + 64 < DIM) {
            #pragma unroll
            for (int i = 0; i < 4; ++i) {
                ax[i]  = *(const float4*)&X[(size_t)(m0 + srow) * DIM + kt + 64 + sc16 + i * 4];
                bx4[i] = *(const float4*)&W[(size_t)(o0 + srow) * DIM + kt + 64 + sc16 + i * 4];
            }
        }

        #pragma unroll
        for (int s = 0; s < 2; ++s) {
            short8 af[2], bf[2];
            #pragma unroll
            for (int mi = 0; mi < 2; ++mi)
                af[mi] = *(const short8*)&As[(wm * 32 + mi * 16 + l16) * LDB + s * 32 + quad * 8];
            #pragma unroll
            for (int ni = 0; ni < 2; ++ni)
                bf[ni] = *(const short8*)&Bs[(wn * 32 + ni * 16 + l16) * LDB + s * 32 + quad * 8];
            #pragma unroll
            for (int ni = 0; ni < 2; ++ni)
                #pragma unroll
                for (int mi = 0; mi < 2; ++mi)
                    acc[mi][ni] = __builtin_amdgcn_mfma_f32_16x16x32_bf16(af[mi], bf[ni], acc[mi][ni], 0, 0, 0);
        }
    }

    const int h = ot;
    #pragma unroll
    for (int mi = 0; mi < 2; ++mi)
        #pragma unroll
        for (int ni = 0; ni < 2; ++ni) {
            const int d = wn * 32 + ni * 16 + l16;
            #pragma unroll
            for (int r = 0; r < 4; ++r) {
                const int m = m0 + wm * 32 + mi * 16 + quad * 4 + r;
                const int n = m >> 10, l = m & (LSEQ - 1);
                float val = acc[mi][ni][r];
                if (sel < 2) val = softplusf_(val);
                obuf[(((size_t)(n * NHEAD + h)) * LSEQ + l) * DH + d] = val;
            }
        }
}

// ---------------------------------------------------------------------------
// Kernel B: per-(c,nh,br) chunk sums.
// ---------------------------------------------------------------------------
__global__ __launch_bounds__(256) void chunksum_kernel(
    const float* __restrict__ kbuf, const float* __restrict__ vbuf,
    const float* __restrict__ pw,
    float* __restrict__ Ssum, float* __restrict__ zsum)
{
    const int c  = blockIdx.x;
    const int nh = blockIdx.y;
    const int br = blockIdx.z;
    const int h  = nh & (NHEAD - 1);
    const int t  = threadIdx.x;

    __shared__ float kf[CHUNK][PAD];
    __shared__ float vt[CHUNK][PAD];

    const size_t base = ((size_t)nh * LSEQ + (size_t)c * CHUNK) * DH;

    #pragma unroll
    for (int i = 0; i < 4; ++i) {
        const int e4 = i * 256 + t;
        const int k  = e4 >> 4;
        const int c4 = (e4 & 15) * 4;
        const float4 kv = *(const float4*)&kbuf[base + (size_t)k * DH + c4];
        const float4 vv = *(const float4*)&vbuf[base + (size_t)k * DH + c4];
        const float4 wv = *(const float4*)&pw[h * DH + c4];
        const float pos = (float)(c * CHUNK + k);
        float4 f;
        if (br == 0)      { f.x = 1.f; f.y = 1.f; f.z = 1.f; f.w = 1.f; }
        else if (br == 1) { f.x = cosf(pos * wv.x); f.y = cosf(pos * wv.y);
                            f.z = cosf(pos * wv.z); f.w = cosf(pos * wv.w); }
        else              { f.x = sinf(pos * wv.x); f.y = sinf(pos * wv.y);
                            f.z = sinf(pos * wv.z); f.w = sinf(pos * wv.w); }
        float4 ko;
        ko.x = kv.x * f.x; ko.y = kv.y * f.y; ko.z = kv.z * f.z; ko.w = kv.w * f.w;
        *(float4*)&kf[k][c4] = ko;
        *(float4*)&vt[k][c4] = vv;
    }
    __syncthreads();

    const int d0 = (t >> 4) * 4;
    const int e0 = (t & 15) * 4;

    float S[4][4] = {};
    float zr[4] = {};
    #pragma unroll 4
    for (int k = 0; k < CHUNK; ++k) {
        const float4 kv = *(const float4*)&kf[k][d0];
        const float4 ve = *(const float4*)&vt[k][e0];
        S[0][0] += kv.x * ve.x; S[0][1] += kv.x * ve.y;
        S[0][2] += kv.x * ve.z; S[0][3] += kv.x * ve.w;
        S[1][0] += kv.y * ve.x; S[1][1] += kv.y * ve.y;
        S[1][2] += kv.y * ve.z; S[1][3] += kv.y * ve.w;
        S[2][0] += kv.z * ve.x; S[2][1] += kv.z * ve.y;
        S[2][2] += kv.z * ve.z; S[2][3] += kv.z * ve.w;
        S[3][0] += kv.w * ve.x; S[3][1] += kv.w * ve.y;
        S[3][2] += kv.w * ve.z; S[3][3] += kv.w * ve.w;
        zr[0] += kv.x; zr[1] += kv.y; zr[2] += kv.z; zr[3] += kv.w;
    }

    float* Sg = Ssum + ((size_t)(br * NHTOT + nh) * NCHUNK + c) * (DH * DH);
    #pragma unroll
    for (int i = 0; i < 4; ++i) {
        float4 o;
        o.x = S[i][0]; o.y = S[i][1]; o.z = S[i][2]; o.w = S[i][3];
        *(float4*)&Sg[(d0 + i) * DH + e0] = o;
    }
    if ((t & 15) == 0) {
        float* zg = zsum + ((size_t)(br * NHTOT + nh) * NCHUNK + c) * DH;
        #pragma unroll
        for (int i = 0; i < 4; ++i) zg[d0 + i] = zr[i];
    }
}

// ---------------------------------------------------------------------------
// Kernel B2: in-place exclusive prefix over chunks; grid (48, 16).
// ---------------------------------------------------------------------------
__global__ __launch_bounds__(256) void scan_kernel(
    float* __restrict__ Ssum, float* __restrict__ zsum)
{
    const int b = blockIdx.x;
    const int s = blockIdx.y;
    const int idx = s * 256 + threadIdx.x;

    float* S = Ssum + (size_t)b * NCHUNK * (DH * DH);
    float v[NCHUNK];
    #pragma unroll
    for (int c = 0; c < NCHUNK; ++c) v[c] = S[c * (DH * DH) + idx];
    float run = 0.f;
    #pragma unroll
    for (int c = 0; c < NCHUNK; ++c) {
        const float nv = v[c];
        S[c * (DH * DH) + idx] = run;
        run += nv;
    }
    if (s == 0 && threadIdx.x < DH) {
        float* z = zsum + (size_t)b * NCHUNK * DH;
        float zv[NCHUNK];
        #pragma unroll
        for (int c = 0; c < NCHUNK; ++c) zv[c] = z[c * DH + threadIdx.x];
        float zr = 0.f;
        #pragma unroll
        for (int c = 0; c < NCHUNK; ++c) {
            const float nv = zv[c];
            z[c * DH + threadIdx.x] = zr;
            zr += nv;
        }
    }
}

// ---------------------------------------------------------------------------
// Kernel C: per-(c,nh,br) partial num/den.  768 blocks = 3/CU for latency
// hiding (measured: 1-block/CU branch-fused variant was ~6-10 us slower).
// ---------------------------------------------------------------------------
__global__ __launch_bounds__(256) void attn_kernel(
    const float* __restrict__ qbuf, const float* __restrict__ kbuf,
    const float* __restrict__ vbuf,
    const float* __restrict__ Ssum, const float* __restrict__ zsum,
    const float* __restrict__ pw, const float* __restrict__ pb,
    float* __restrict__ numP, float* __restrict__ denP)
{
    const int c  = blockIdx.x;
    const int nh = blockIdx.y;
    const int br = blockIdx.z;
    const int n  = nh >> 3;
    const int h  = nh & (NHEAD - 1);
    const int t  = threadIdx.x;

    __shared__ float qT[DH][PAD];
    __shared__ float kT[DH][PAD];
    __shared__ float At[CHUNK][PAD];
    __shared__ float zl[DH];
    __shared__ float dl[CHUNK];
    __shared__ float dpart[4][CHUNK];

    const int l0 = (t >> 4) * 4;
    const int e0 = (t & 15) * 4;
    const size_t base = ((size_t)nh * LSEQ + (size_t)c * CHUNK) * DH;
    const int dcol = t & 63;
    const int rg = (t >> 6) * 16;

    const float w = pw[h * DH + dcol];
    const float bias = 3.14159265358979323846f / (1.f + expf(-pb[h * DH + dcol]));

    #pragma unroll
    for (int j = 0; j < 16; ++j) {
        const int l = rg + j;
        const float q = qbuf[base + (size_t)l * DH + dcol];
        const float k = kbuf[base + (size_t)l * DH + dcol];
        const float pos = (float)(c * CHUNK + l);
        float tq = 1.f, tk = 1.f;
        if (br == 1) { tq = cosf(pos * w + bias); tk = cosf(pos * w); }
        else if (br == 2) { tq = sinf(pos * w + bias); tk = sinf(pos * w); }
        qT[dcol][l] = q * tq;
        kT[dcol][l] = k * tk;
    }
    if (t < DH)
        zl[t] = zsum[((size_t)(br * NHTOT + nh) * NCHUNK + c) * DH + t];
    __syncthreads();

    const float* Sg = Ssum + ((size_t)(br * NHTOT + nh) * NCHUNK + c) * (DH * DH);

    float num[4][4] = {};
    float Ar[4][4] = {};
    float den[4] = {};

    #pragma unroll 4
    for (int d = 0; d < DH; ++d) {
        const float4 qv = *(const float4*)&qT[d][l0];
        const float4 kv = *(const float4*)&kT[d][e0];
        const float4 Sv = *(const float4*)&Sg[d * DH + e0];
        const float z = zl[d];
        num[0][0] += qv.x * Sv.x; num[0][1] += qv.x * Sv.y;
        num[0][2] += qv.x * Sv.z; num[0][3] += qv.x * Sv.w;
        num[1][0] += qv.y * Sv.x; num[1][1] += qv.y * Sv.y;
        num[1][2] += qv.y * Sv.z; num[1][3] += qv.y * Sv.w;
        num[2][0] += qv.z * Sv.x; num[2][1] += qv.z * Sv.y;
        num[2][2] += qv.z * Sv.z; num[2][3] += qv.z * Sv.w;
        num[3][0] += qv.w * Sv.x; num[3][1] += qv.w * Sv.y;
        num[3][2] += qv.w * Sv.z; num[3][3] += qv.w * Sv.w;
        Ar[0][0] += qv.x * kv.x; Ar[0][1] += qv.x * kv.y;
        Ar[0][2] += qv.x * kv.z; Ar[0][3] += qv.x * kv.w;
        Ar[1][0] += qv.y * kv.x; Ar[1][1] += qv.y * kv.y;
        Ar[1][2] += qv.y * kv.z; Ar[1][3] += qv.y * kv.w;
        Ar[2][0] += qv.z * kv.x; Ar[2][1] += qv.z * kv.y;
        Ar[2][2] += qv.z * kv.z; Ar[2][3] += qv.z * kv.w;
        Ar[3][0] += qv.w * kv.x; Ar[3][1] += qv.w * kv.y;
        Ar[3][2] += qv.w * kv.z; Ar[3][3] += qv.w * kv.w;
        den[0] += qv.x * z; den[1] += qv.y * z;
        den[2] += qv.z * z; den[3] += qv.w * z;
    }

    #pragma unroll
    for (int i = 0; i < 4; ++i)
        #pragma unroll
        for (int j = 0; j < 4; ++j) {
            const int l = l0 + i, k = e0 + j;
            At[k][l] = (k <= l) ? Ar[i][j] : 0.f;
        }
    if ((t & 15) == 0) {
        #pragma unroll
        for (int i = 0; i < 4; ++i) dl[l0 + i] = den[i];
    }
    __syncthreads();

    {
        const int col = t & 63, seg = t >> 6;
        float s = 0.f;
        #pragma unroll
        for (int j = 0; j < 16; ++j) s += At[seg * 16 + j][col];
        dpart[seg][col] = s;
    }
    __syncthreads();
    if (t < DH) dl[t] += dpart[0][t] + dpart[1][t] + dpart[2][t] + dpart[3][t];
    __syncthreads();

    #pragma unroll 2
    for (int k = 0; k < CHUNK; ++k) {
        const float4 av = *(const float4*)&At[k][l0];
        const float4 vv = *(const float4*)&vbuf[base + (size_t)k * DH + e0];
        num[0][0] += av.x * vv.x; num[0][1] += av.x * vv.y;
        num[0][2] += av.x * vv.z; num[0][3] += av.x * vv.w;
        num[1][0] += av.y * vv.x; num[1][1] += av.y * vv.y;
        num[1][2] += av.y * vv.z; num[1][3] += av.y * vv.w;
        num[2][0] += av.z * vv.x; num[2][1] += av.z * vv.y;
        num[2][2] += av.z * vv.z; num[2][3] += av.z * vv.w;
        num[3][0] += av.w * vv.x; num[3][1] += av.w * vv.y;
        num[3][2] += av.w * vv.z; num[3][3] += av.w * vv.w;
    }

    #pragma unroll
    for (int i = 0; i < 4; ++i) {
        const int l = c * CHUNK + l0 + i;
        float4 o;
        o.x = num[i][0]; o.y = num[i][1]; o.z = num[i][2]; o.w = num[i][3];
        *(float4*)&numP[(((size_t)br * 2 + n) * LSEQ + l) * DIM + h * DH + e0] = o;
    }
    if ((t & 15) == 0) {
        #pragma unroll
        for (int i = 0; i < 4; ++i)
            denP[((size_t)(br * NHTOT + nh)) * LSEQ + c * CHUNK + l0 + i] = dl[l0 + i];
    }
}

// ---------------------------------------------------------------------------
// Kernel D: out = (num0+num1+num2) / (den0+den1+den2).
// ---------------------------------------------------------------------------
__global__ __launch_bounds__(256) void combine_kernel(
    const float* __restrict__ numP, const float* __restrict__ denP,
    float* __restrict__ outp)
{
    const int i = blockIdx.x * 256 + threadIdx.x;
    const int row = i >> 7;
    const int ci  = i & 127;
    const int n = row >> 10, l = row & (LSEQ - 1), h = ci >> 4;
    const int nh = n * NHEAD + h;
    const float4* N = (const float4*)numP;
    const float4 a = N[i];
    const float4 b = N[i + 262144];
    const float4 cc = N[i + 524288];
    const float ds = denP[(size_t)nh * LSEQ + l]
                   + denP[((size_t)NHTOT + nh) * LSEQ + l]
                   + denP[((size_t)2 * NHTOT + nh) * LSEQ + l];
    const float inv = 1.f / ds;
    float4 o;
    o.x = (a.x + b.x + cc.x) * inv;
    o.y = (a.y + b.y + cc.y) * inv;
    o.z = (a.z + b.z + cc.z) * inv;
    o.w = (a.w + b.w + cc.w) * inv;
    ((float4*)outp)[i] = o;
}

extern "C" void kernel_launch(void* const* d_in, const int* in_sizes, int n_in,
                              void* d_out, int out_size, void* d_ws, size_t ws_size,
                              hipStream_t stream) {
    const float* query = (const float*)d_in[0];
    const float* key   = (const float*)d_in[1];
    const float* Wq    = (const float*)d_in[2];
    const float* Wk    = (const float*)d_in[3];
    const float* Wv    = (const float*)d_in[4];
    const float* pw    = (const float*)d_in[5];
    const float* pb    = (const float*)d_in[6];

    float* F = (float*)d_ws;
    float* qbuf = F;                 // 1,048,576
    float* kbuf = F + 1048576;
    float* vbuf = F + 2097152;
    float* Ssum = F + 3145728;       // 3,145,728
    float* zsum = F + 6291456;       // 49,152
    float* numP = F + 6340608;       // 3,145,728
    float* denP = F + 9486336;       // 49,152 -> 38.1 MB total

    proj_kernel<<<dim3(32, 8, 3), 256, 0, stream>>>(
        query, key, Wq, Wk, Wv, qbuf, kbuf, vbuf);
    chunksum_kernel<<<dim3(NCHUNK, NHTOT, 3), 256, 0, stream>>>(
        kbuf, vbuf, pw, Ssum, zsum);
    scan_kernel<<<dim3(3 * NHTOT, NCHUNK), 256, 0, stream>>>(Ssum, zsum);
    attn_kernel<<<dim3(NCHUNK, NHTOT, 3), 256, 0, stream>>>(
        qbuf, kbuf, vbuf, Ssum, zsum, pw, pb, numP, denP);
    combine_kernel<<<dim3(1024), 256, 0, stream>>>(numP, denP, (float*)d_out);
}

// Round 7
// 123.681 us; speedup vs baseline: 1.4806x; 1.1068x over previous
//
#include <hip/hip_runtime.h>
#include <hip/hip_bf16.h>

#define LSEQ   1024
#define NHEAD  8
#define DH     64
#define DIM    512
#define CHUNK  64
#define NCHUNK 16
#define NHTOT  16
#define PAD    68    // f32 LDS row pad
#define LDB    68    // ushort LDS row stride for proj
#define LDA    72    // ushort LDS row stride for attn (144 B, 16B-aligned frags)

typedef __attribute__((ext_vector_type(8))) short short8;
typedef __attribute__((ext_vector_type(4))) float floatx4;

__device__ __forceinline__ float softplusf_(float x) {
    if (x > 20.f) return x;
    return log1pf(expf(x));
}
__device__ __forceinline__ unsigned short bf16_rne(float x) {
    unsigned int u = __float_as_uint(x);
    u += 0x7FFFu + ((u >> 16) & 1u);
    return (unsigned short)(u >> 16);
}
__device__ __forceinline__ float bf16_tof(unsigned short h) {
    return __uint_as_float(((unsigned int)h) << 16);
}

// ---------------------------------------------------------------------------
// Kernel A: C = X @ W^T, single-pass bf16 MFMA.  64x64 tile, grid (32,8,3).
// ---------------------------------------------------------------------------
__global__ __launch_bounds__(256) void proj_kernel(
    const float* __restrict__ query, const float* __restrict__ key,
    const float* __restrict__ Wq, const float* __restrict__ Wk,
    const float* __restrict__ Wv,
    float* __restrict__ qbuf, float* __restrict__ kbuf, float* __restrict__ vbuf)
{
    const int mt  = blockIdx.x;
    const int ot  = blockIdx.y;
    const int sel = blockIdx.z;
    const int t   = threadIdx.x;

    const float* __restrict__ X = (sel == 0) ? query : key;
    const float* __restrict__ W = (sel == 0) ? Wq : (sel == 1) ? Wk : Wv;
    float* __restrict__ obuf = (sel == 0) ? qbuf : (sel == 1) ? kbuf : vbuf;

    __shared__ unsigned short As[64 * LDB];
    __shared__ unsigned short Bs[64 * LDB];

    const int m0 = mt * 64, o0 = ot * 64;
    const int lane = t & 63, wave = t >> 6;
    const int quad = lane >> 4, l16 = lane & 15;
    const int wm = wave >> 1, wn = wave & 1;

    const int srow = t >> 2;
    const int sc16 = (t & 3) * 16;

    floatx4 acc[2][2];
    #pragma unroll
    for (int i = 0; i < 2; ++i)
        #pragma unroll
        for (int j = 0; j < 2; ++j) acc[i][j] = (floatx4){0.f, 0.f, 0.f, 0.f};

    float4 ax[4], bx4[4];
    #pragma unroll
    for (int i = 0; i < 4; ++i) {
        ax[i]  = *(const float4*)&X[(size_t)(m0 + srow) * DIM + sc16 + i * 4];
        bx4[i] = *(const float4*)&W[(size_t)(o0 + srow) * DIM + sc16 + i * 4];
    }

    for (int kt = 0; kt < DIM; kt += 64) {
        __syncthreads();
        {
            short8 a0, a1, b0, b1;
            #pragma unroll
            for (int i = 0; i < 2; ++i) {
                const float va[4] = {ax[i].x, ax[i].y, ax[i].z, ax[i].w};
                const float vb[4] = {bx4[i].x, bx4[i].y, bx4[i].z, bx4[i].w};
                #pragma unroll
                for (int j = 0; j < 4; ++j) {
                    a0[i * 4 + j] = (short)bf16_rne(va[j]);
                    b0[i * 4 + j] = (short)bf16_rne(vb[j]);
                }
            }
            #pragma unroll
            for (int i = 2; i < 4; ++i) {
                const float va[4] = {ax[i].x, ax[i].y, ax[i].z, ax[i].w};
                const float vb[4] = {bx4[i].x, bx4[i].y, bx4[i].z, bx4[i].w};
                #pragma unroll
                for (int j = 0; j < 4; ++j) {
                    a1[(i - 2) * 4 + j] = (short)bf16_rne(va[j]);
                    b1[(i - 2) * 4 + j] = (short)bf16_rne(vb[j]);
                }
            }
            *(short8*)&As[srow * LDB + sc16]     = a0;
            *(short8*)&As[srow * LDB + sc16 + 8] = a1;
            *(short8*)&Bs[srow * LDB + sc16]     = b0;
            *(short8*)&Bs[srow * LDB + sc16 + 8] = b1;
        }
        __syncthreads();

        if (kt + 64 < DIM) {
            #pragma unroll
            for (int i = 0; i < 4; ++i) {
                ax[i]  = *(const float4*)&X[(size_t)(m0 + srow) * DIM + kt + 64 + sc16 + i * 4];
                bx4[i] = *(const float4*)&W[(size_t)(o0 + srow) * DIM + kt + 64 + sc16 + i * 4];
            }
        }

        #pragma unroll
        for (int s = 0; s < 2; ++s) {
            short8 af[2], bf[2];
            #pragma unroll
            for (int mi = 0; mi < 2; ++mi)
                af[mi] = *(const short8*)&As[(wm * 32 + mi * 16 + l16) * LDB + s * 32 + quad * 8];
            #pragma unroll
            for (int ni = 0; ni < 2; ++ni)
                bf[ni] = *(const short8*)&Bs[(wn * 32 + ni * 16 + l16) * LDB + s * 32 + quad * 8];
            #pragma unroll
            for (int ni = 0; ni < 2; ++ni)
                #pragma unroll
                for (int mi = 0; mi < 2; ++mi)
                    acc[mi][ni] = __builtin_amdgcn_mfma_f32_16x16x32_bf16(af[mi], bf[ni], acc[mi][ni], 0, 0, 0);
        }
    }

    const int h = ot;
    #pragma unroll
    for (int mi = 0; mi < 2; ++mi)
        #pragma unroll
        for (int ni = 0; ni < 2; ++ni) {
            const int d = wn * 32 + ni * 16 + l16;
            #pragma unroll
            for (int r = 0; r < 4; ++r) {
                const int m = m0 + wm * 32 + mi * 16 + quad * 4 + r;
                const int n = m >> 10, l = m & (LSEQ - 1);
                float val = acc[mi][ni][r];
                if (sel < 2) val = softplusf_(val);
                obuf[(((size_t)(n * NHEAD + h)) * LSEQ + l) * DH + d] = val;
            }
        }
}

// ---------------------------------------------------------------------------
// Kernel B: per-(c,nh,br) chunk sums, stored TRANSPOSED:
//   Ssum[br][nh][c][e][d] = sum_k v[k][e] * kf[k][d];  zsum[...][d] = sum_k kf[k][d]
// ---------------------------------------------------------------------------
__global__ __launch_bounds__(256) void chunksum_kernel(
    const float* __restrict__ kbuf, const float* __restrict__ vbuf,
    const float* __restrict__ pw,
    float* __restrict__ Ssum, float* __restrict__ zsum)
{
    const int c  = blockIdx.x;
    const int nh = blockIdx.y;
    const int br = blockIdx.z;
    const int h  = nh & (NHEAD - 1);
    const int t  = threadIdx.x;

    __shared__ float kf[CHUNK][PAD];
    __shared__ float vt[CHUNK][PAD];

    const size_t base = ((size_t)nh * LSEQ + (size_t)c * CHUNK) * DH;

    #pragma unroll
    for (int i = 0; i < 4; ++i) {
        const int e4 = i * 256 + t;
        const int k  = e4 >> 4;
        const int c4 = (e4 & 15) * 4;
        const float4 kv = *(const float4*)&kbuf[base + (size_t)k * DH + c4];
        const float4 vv = *(const float4*)&vbuf[base + (size_t)k * DH + c4];
        const float4 wv = *(const float4*)&pw[h * DH + c4];
        const float pos = (float)(c * CHUNK + k);
        float4 f;
        if (br == 0)      { f.x = 1.f; f.y = 1.f; f.z = 1.f; f.w = 1.f; }
        else if (br == 1) { f.x = cosf(pos * wv.x); f.y = cosf(pos * wv.y);
                            f.z = cosf(pos * wv.z); f.w = cosf(pos * wv.w); }
        else              { f.x = sinf(pos * wv.x); f.y = sinf(pos * wv.y);
                            f.z = sinf(pos * wv.z); f.w = sinf(pos * wv.w); }
        float4 ko;
        ko.x = kv.x * f.x; ko.y = kv.y * f.y; ko.z = kv.z * f.z; ko.w = kv.w * f.w;
        *(float4*)&kf[k][c4] = ko;
        *(float4*)&vt[k][c4] = vv;
    }
    __syncthreads();

    const int d0 = (t >> 4) * 4;   // row block  (e index of S^T)
    const int e0 = (t & 15) * 4;   // col block  (d index of S^T)

    float S[4][4] = {};
    float zr[4] = {};
    #pragma unroll 4
    for (int k = 0; k < CHUNK; ++k) {
        const float4 rv = *(const float4*)&vt[k][d0];   // rows: e
        const float4 cv = *(const float4*)&kf[k][e0];   // cols: d
        S[0][0] += rv.x * cv.x; S[0][1] += rv.x * cv.y;
        S[0][2] += rv.x * cv.z; S[0][3] += rv.x * cv.w;
        S[1][0] += rv.y * cv.x; S[1][1] += rv.y * cv.y;
        S[1][2] += rv.y * cv.z; S[1][3] += rv.y * cv.w;
        S[2][0] += rv.z * cv.x; S[2][1] += rv.z * cv.y;
        S[2][2] += rv.z * cv.z; S[2][3] += rv.z * cv.w;
        S[3][0] += rv.w * cv.x; S[3][1] += rv.w * cv.y;
        S[3][2] += rv.w * cv.z; S[3][3] += rv.w * cv.w;
        zr[0] += cv.x; zr[1] += cv.y; zr[2] += cv.z; zr[3] += cv.w;
    }

    float* Sg = Ssum + ((size_t)(br * NHTOT + nh) * NCHUNK + c) * (DH * DH);
    #pragma unroll
    for (int i = 0; i < 4; ++i) {
        float4 o;
        o.x = S[i][0]; o.y = S[i][1]; o.z = S[i][2]; o.w = S[i][3];
        *(float4*)&Sg[(d0 + i) * DH + e0] = o;   // [e][d]
    }
    if ((t >> 4) == 0) {   // threads 0..15 cover d = 0..63
        float* zg = zsum + ((size_t)(br * NHTOT + nh) * NCHUNK + c) * DH;
        #pragma unroll
        for (int i = 0; i < 4; ++i) zg[e0 + i] = zr[i];
    }
}

// ---------------------------------------------------------------------------
// Kernel B2: in-place exclusive prefix over chunks; grid (48, 16). Layout-agnostic.
// ---------------------------------------------------------------------------
__global__ __launch_bounds__(256) void scan_kernel(
    float* __restrict__ Ssum, float* __restrict__ zsum)
{
    const int b = blockIdx.x;
    const int s = blockIdx.y;
    const int idx = s * 256 + threadIdx.x;

    float* S = Ssum + (size_t)b * NCHUNK * (DH * DH);
    float v[NCHUNK];
    #pragma unroll
    for (int c = 0; c < NCHUNK; ++c) v[c] = S[c * (DH * DH) + idx];
    float run = 0.f;
    #pragma unroll
    for (int c = 0; c < NCHUNK; ++c) {
        const float nv = v[c];
        S[c * (DH * DH) + idx] = run;
        run += nv;
    }
    if (s == 0 && threadIdx.x < DH) {
        float* z = zsum + (size_t)b * NCHUNK * DH;
        float zv[NCHUNK];
        #pragma unroll
        for (int c = 0; c < NCHUNK; ++c) zv[c] = z[c * DH + threadIdx.x];
        float zr = 0.f;
        #pragma unroll
        for (int c = 0; c < NCHUNK; ++c) {
            const float nv = zv[c];
            z[c * DH + threadIdx.x] = zr;
            zr += nv;
        }
    }
}

// ---------------------------------------------------------------------------
// Kernel C (MFMA): per-(c,nh,br) partial num/den.  Three 64x64x64 bf16 GEMMs:
//   scores = qf*kf^T (masked), num = qf*Sp + scores*v.  den from same bf16 LDS.
// num and den use identical quantized operands -> ratio errors partially cancel.
// ---------------------------------------------------------------------------
__global__ __launch_bounds__(256) void attn_kernel(
    const float* __restrict__ qbuf, const float* __restrict__ kbuf,
    const float* __restrict__ vbuf,
    const float* __restrict__ Ssum, const float* __restrict__ zsum,
    const float* __restrict__ pw, const float* __restrict__ pb,
    float* __restrict__ numP, float* __restrict__ denP)
{
    const int c  = blockIdx.x;
    const int nh = blockIdx.y;
    const int br = blockIdx.z;
    const int n  = nh >> 3;
    const int h  = nh & (NHEAD - 1);
    const int t  = threadIdx.x;
    const int lane = t & 63, wave = t >> 6;
    const int quad = lane >> 4, l16 = lane & 15;
    const int wm = wave >> 1, wn = wave & 1;

    __shared__ unsigned short qfL[64 * LDA];  // [l][d]
    __shared__ unsigned short kfL[64 * LDA];  // [k][d]
    __shared__ unsigned short vTL[64 * LDA];  // [e][k]
    __shared__ unsigned short SpL[64 * LDA];  // [e][d]  (S^T prefix)
    __shared__ unsigned short scA[64 * LDA];  // masked scores [l][k]
    __shared__ float zl[DH];
    __shared__ float dpart[8][64];

    const size_t base = ((size_t)nh * LSEQ + (size_t)c * CHUNK) * DH;
    const float* Sg = Ssum + ((size_t)(br * NHTOT + nh) * NCHUNK + c) * (DH * DH);
    const float PI_ = 3.14159265358979323846f;

    // ---- staging: 16 elems/thread/array, all bf16 ----
    #pragma unroll
    for (int i = 0; i < 4; ++i) {
        const int idx = i * 256 + t;
        const int r  = idx >> 4;          // row: l / k / e
        const int c4 = (idx & 15) * 4;    // col base: d / e / d
        const float4 qv = *(const float4*)&qbuf[base + (size_t)r * DH + c4];
        const float4 kv = *(const float4*)&kbuf[base + (size_t)r * DH + c4];
        const float4 vv = *(const float4*)&vbuf[base + (size_t)r * DH + c4];
        const float4 sv = *(const float4*)&Sg[r * DH + c4];
        float tq[4] = {1.f, 1.f, 1.f, 1.f}, tk[4] = {1.f, 1.f, 1.f, 1.f};
        if (br != 0) {
            const float4 wv  = *(const float4*)&pw[h * DH + c4];
            const float4 pbv = *(const float4*)&pb[h * DH + c4];
            const float w4[4] = {wv.x, wv.y, wv.z, wv.w};
            const float b4[4] = {pbv.x, pbv.y, pbv.z, pbv.w};
            const float pos = (float)(c * CHUNK + r);
            #pragma unroll
            for (int j = 0; j < 4; ++j) {
                const float bias = PI_ / (1.f + expf(-b4[j]));
                if (br == 1) { tq[j] = cosf(pos * w4[j] + bias); tk[j] = cosf(pos * w4[j]); }
                else         { tq[j] = sinf(pos * w4[j] + bias); tk[j] = sinf(pos * w4[j]); }
            }
        }
        const float q4[4] = {qv.x, qv.y, qv.z, qv.w};
        const float k4[4] = {kv.x, kv.y, kv.z, kv.w};
        const float v4[4] = {vv.x, vv.y, vv.z, vv.w};
        const float s4[4] = {sv.x, sv.y, sv.z, sv.w};
        ushort4 qh, kh, sh;
        unsigned short* pq = (unsigned short*)&qh;
        unsigned short* pk = (unsigned short*)&kh;
        unsigned short* ps = (unsigned short*)&sh;
        #pragma unroll
        for (int j = 0; j < 4; ++j) {
            pq[j] = bf16_rne(q4[j] * tq[j]);
            pk[j] = bf16_rne(k4[j] * tk[j]);
            ps[j] = bf16_rne(s4[j]);
            vTL[(c4 + j) * LDA + r] = bf16_rne(v4[j]);   // transpose
        }
        *(ushort4*)&qfL[r * LDA + c4] = qh;
        *(ushort4*)&kfL[r * LDA + c4] = kh;
        *(ushort4*)&SpL[r * LDA + c4] = sh;
    }
    if (t < DH)
        zl[t] = zsum[((size_t)(br * NHTOT + nh) * NCHUNK + c) * DH + t];
    __syncthreads();

    // ---- GEMM1 (scores) + GEMM2 (num from S-prefix) ----
    floatx4 acc1[2][2], acc2[2][2];
    #pragma unroll
    for (int i = 0; i < 2; ++i)
        #pragma unroll
        for (int j = 0; j < 2; ++j) {
            acc1[i][j] = (floatx4){0.f, 0.f, 0.f, 0.f};
            acc2[i][j] = (floatx4){0.f, 0.f, 0.f, 0.f};
        }
    #pragma unroll
    for (int kk = 0; kk < 2; ++kk) {
        short8 a[2], b1[2], b2[2];
        #pragma unroll
        for (int mi = 0; mi < 2; ++mi)
            a[mi] = *(const short8*)&qfL[(wm * 32 + mi * 16 + l16) * LDA + kk * 32 + quad * 8];
        #pragma unroll
        for (int ni = 0; ni < 2; ++ni) {
            b1[ni] = *(const short8*)&kfL[(wn * 32 + ni * 16 + l16) * LDA + kk * 32 + quad * 8];
            b2[ni] = *(const short8*)&SpL[(wn * 32 + ni * 16 + l16) * LDA + kk * 32 + quad * 8];
        }
        #pragma unroll
        for (int ni = 0; ni < 2; ++ni)
            #pragma unroll
            for (int mi = 0; mi < 2; ++mi) {
                acc1[mi][ni] = __builtin_amdgcn_mfma_f32_16x16x32_bf16(a[mi], b1[ni], acc1[mi][ni], 0, 0, 0);
                acc2[mi][ni] = __builtin_amdgcn_mfma_f32_16x16x32_bf16(a[mi], b2[ni], acc2[mi][ni], 0, 0, 0);
            }
    }

    // den part 1: qf . z  (wave w handles 16-d segment w for all 64 l)
    {
        const int l = t & 63, seg = t >> 6;
        float s = 0.f;
        #pragma unroll
        for (int j2 = 0; j2 < 2; ++j2) {
            const short8 v8 = *(const short8*)&qfL[l * LDA + seg * 16 + j2 * 8];
            #pragma unroll
            for (int j = 0; j < 8; ++j)
                s += bf16_tof((unsigned short)v8[j]) * zl[seg * 16 + j2 * 8 + j];
        }
        dpart[seg][l] = s;
    }

    // write masked scores (C-layout -> [l][k] bf16); own buffer, no pre-sync
    #pragma unroll
    for (int mi = 0; mi < 2; ++mi)
        #pragma unroll
        for (int ni = 0; ni < 2; ++ni) {
            const int kcol = wn * 32 + ni * 16 + l16;
            #pragma unroll
            for (int r = 0; r < 4; ++r) {
                const int lrow = wm * 32 + mi * 16 + quad * 4 + r;
                const float v = (kcol <= lrow) ? acc1[mi][ni][r] : 0.f;
                scA[lrow * LDA + kcol] = bf16_rne(v);
            }
        }
    __syncthreads();

    // ---- GEMM3: num += scores * v ----
    #pragma unroll
    for (int kk = 0; kk < 2; ++kk) {
        short8 a[2], b[2];
        #pragma unroll
        for (int mi = 0; mi < 2; ++mi)
            a[mi] = *(const short8*)&scA[(wm * 32 + mi * 16 + l16) * LDA + kk * 32 + quad * 8];
        #pragma unroll
        for (int ni = 0; ni < 2; ++ni)
            b[ni] = *(const short8*)&vTL[(wn * 32 + ni * 16 + l16) * LDA + kk * 32 + quad * 8];
        #pragma unroll
        for (int ni = 0; ni < 2; ++ni)
            #pragma unroll
            for (int mi = 0; mi < 2; ++mi)
                acc2[mi][ni] = __builtin_amdgcn_mfma_f32_16x16x32_bf16(a[mi], b[ni], acc2[mi][ni], 0, 0, 0);
    }

    // den part 2: row sums of masked scores
    {
        const int l = t & 63, seg = t >> 6;
        float s = 0.f;
        #pragma unroll
        for (int j2 = 0; j2 < 2; ++j2) {
            const short8 v8 = *(const short8*)&scA[l * LDA + seg * 16 + j2 * 8];
            #pragma unroll
            for (int j = 0; j < 8; ++j) s += bf16_tof((unsigned short)v8[j]);
        }
        dpart[4 + seg][l] = s;
    }
    __syncthreads();

    if (t < DH) {
        const float dl = dpart[0][t] + dpart[1][t] + dpart[2][t] + dpart[3][t]
                       + dpart[4][t] + dpart[5][t] + dpart[6][t] + dpart[7][t];
        denP[((size_t)(br * NHTOT + nh)) * LSEQ + c * CHUNK + t] = dl;
    }

    // epilogue: raw partial numerator
    #pragma unroll
    for (int mi = 0; mi < 2; ++mi)
        #pragma unroll
        for (int ni = 0; ni < 2; ++ni) {
            const int e = wn * 32 + ni * 16 + l16;
            #pragma unroll
            for (int r = 0; r < 4; ++r) {
                const int l = c * CHUNK + wm * 32 + mi * 16 + quad * 4 + r;
                numP[(((size_t)br * 2 + n) * LSEQ + l) * DIM + h * DH + e] = acc2[mi][ni][r];
            }
        }
}

// ---------------------------------------------------------------------------
// Kernel D: out = (num0+num1+num2) / (den0+den1+den2).
// ---------------------------------------------------------------------------
__global__ __launch_bounds__(256) void combine_kernel(
    const float* __restrict__ numP, const float* __restrict__ denP,
    float* __restrict__ outp)
{
    const int i = blockIdx.x * 256 + threadIdx.x;
    const int row = i >> 7;
    const int ci  = i & 127;
    const int n = row >> 10, l = row & (LSEQ - 1), h = ci >> 4;
    const int nh = n * NHEAD + h;
    const float4* N = (const float4*)numP;
    const float4 a = N[i];
    const float4 b = N[i + 262144];
    const float4 cc = N[i + 524288];
    const float ds = denP[(size_t)nh * LSEQ + l]
                   + denP[((size_t)NHTOT + nh) * LSEQ + l]
                   + denP[((size_t)2 * NHTOT + nh) * LSEQ + l];
    const float inv = 1.f / ds;
    float4 o;
    o.x = (a.x + b.x + cc.x) * inv;
    o.y = (a.y + b.y + cc.y) * inv;
    o.z = (a.z + b.z + cc.z) * inv;
    o.w = (a.w + b.w + cc.w) * inv;
    ((float4*)outp)[i] = o;
}

extern "C" void kernel_launch(void* const* d_in, const int* in_sizes, int n_in,
                              void* d_out, int out_size, void* d_ws, size_t ws_size,
                              hipStream_t stream) {
    const float* query = (const float*)d_in[0];
    const float* key   = (const float*)d_in[1];
    const float* Wq    = (const float*)d_in[2];
    const float* Wk    = (const float*)d_in[3];
    const float* Wv    = (const float*)d_in[4];
    const float* pw    = (const float*)d_in[5];
    const float* pb    = (const float*)d_in[6];

    float* F = (float*)d_ws;
    float* qbuf = F;                 // 1,048,576
    float* kbuf = F + 1048576;
    float* vbuf = F + 2097152;
    float* Ssum = F + 3145728;       // 3,145,728  ([br][nh][c][e][d])
    float* zsum = F + 6291456;       // 49,152
    float* numP = F + 6340608;       // 3,145,728
    float* denP = F + 9486336;       // 49,152 -> 38.1 MB total

    proj_kernel<<<dim3(32, 8, 3), 256, 0, stream>>>(
        query, key, Wq, Wk, Wv, qbuf, kbuf, vbuf);
    chunksum_kernel<<<dim3(NCHUNK, NHTOT, 3), 256, 0, stream>>>(
        kbuf, vbuf, pw, Ssum, zsum);
    scan_kernel<<<dim3(3 * NHTOT, NCHUNK), 256, 0, stream>>>(Ssum, zsum);
    attn_kernel<<<dim3(NCHUNK, NHTOT, 3), 256, 0, stream>>>(
        qbuf, kbuf, vbuf, Ssum, zsum, pw, pb, numP, denP);
    combine_kernel<<<dim3(1024), 256, 0, stream>>>(numP, denP, (float*)d_out);
}